// Round 8
// baseline (2489.586 us; speedup 1.0000x reference)
//
#include <hip/hip_runtime.h>
#include <hip/hip_bf16.h>
#include <stdint.h>

#define Dd 1024
#define Hd 2048
#define Od 1024
#define Ed 8
#define Nd 4096

typedef __bf16 bf16x8 __attribute__((ext_vector_type(8)));
typedef float f32x4 __attribute__((ext_vector_type(4)));

__device__ __forceinline__ void gload16(const void* g, void* l) {
  __builtin_amdgcn_global_load_lds(
      (const __attribute__((address_space(1))) void*)g,
      (__attribute__((address_space(3))) void*)l, 16, 0, 0);
}

__device__ __forceinline__ unsigned short f2bf(float f) {
  __hip_bfloat16 h = __float2bfloat16(f);
  return *reinterpret_cast<unsigned short*>(&h);
}

// ---------- f32 -> bf16 conversion, 8 elems / thread ----------
__global__ void cvt_kernel(const float* __restrict__ in,
                           unsigned short* __restrict__ out, int ngroups) {
  int stride = gridDim.x * blockDim.x;
  for (int g = blockIdx.x * blockDim.x + threadIdx.x; g < ngroups; g += stride) {
    const float4* p = (const float4*)(in + (size_t)g * 8);
    float4 a = p[0], b = p[1];
    unsigned short o[8];
    o[0] = f2bf(a.x); o[1] = f2bf(a.y); o[2] = f2bf(a.z); o[3] = f2bf(a.w);
    o[4] = f2bf(b.x); o[5] = f2bf(b.y); o[6] = f2bf(b.z); o[7] = f2bf(b.w);
    *(int4*)(out + (size_t)g * 8) = *(int4*)o;
  }
}

// ---------- router (also emits xb bf16) ----------
__global__ void router_kernel(const float* __restrict__ x, const float* __restrict__ Wr,
                              const float* __restrict__ br, float* __restrict__ route,
                              unsigned short* __restrict__ xb) {
  const int n = blockIdx.x;
  const int t = threadIdx.x;  // 256
  __shared__ float xs[Dd];
  float4 v = *(const float4*)&x[(size_t)n * Dd + t * 4];
  *(float4*)&xs[t * 4] = v;
  unsigned short o[4] = {f2bf(v.x), f2bf(v.y), f2bf(v.z), f2bf(v.w)};
  *(uint2*)&xb[(size_t)n * Dd + t * 4] = *(const uint2*)o;
  __syncthreads();
  float p[Ed];
  #pragma unroll
  for (int e = 0; e < Ed; ++e) p[e] = 0.f;
  for (int d = t; d < Dd; d += 256) {
    float xv = xs[d];
    #pragma unroll
    for (int e = 0; e < Ed; ++e) p[e] += xv * Wr[e * Dd + d];
  }
  __shared__ float red[Ed][4];
  const int lane = t & 63, wid = t >> 6;
  #pragma unroll
  for (int e = 0; e < Ed; ++e) {
    float vv = p[e];
    for (int off = 32; off > 0; off >>= 1) vv += __shfl_down(vv, off);
    if (lane == 0) red[e][wid] = vv;
  }
  __syncthreads();
  if (t == 0) {
    float lg[Ed], mx = -1e30f;
    #pragma unroll
    for (int e = 0; e < Ed; ++e) {
      lg[e] = red[e][0] + red[e][1] + red[e][2] + red[e][3] + br[e];
      mx = fmaxf(mx, lg[e]);
    }
    float s = 0.f;
    #pragma unroll
    for (int e = 0; e < Ed; ++e) { lg[e] = expf(lg[e] - mx); s += lg[e]; }
    float inv = 1.f / s;
    #pragma unroll
    for (int e = 0; e < Ed; ++e) route[(size_t)n * Ed + e] = lg[e] * inv;
  }
}

// ---------- out init: out[n,o] = sum_e route[n,e] * b2[e,o] ----------
__global__ void init_out_kernel(const float* __restrict__ route, const float* __restrict__ b2,
                                float* __restrict__ out) {
  const int idx = blockIdx.x * 256 + threadIdx.x;
  const int n = idx >> 10, o = idx & (Od - 1);
  float s = 0.f;
  #pragma unroll
  for (int e = 0; e < Ed; ++e) s += route[(size_t)n * Ed + e] * b2[e * Od + o];
  out[idx] = s;
}

// ============ 256x256 BK=32 GEMM, 64KB LDS -> 2 blocks/CU ============
// Mechanism: cross-BLOCK overlap. Two independent blocks per CU mean one
// block's MFMA phase covers the other's ds_read/staging phase with no
// schedule engineering (m97/m114 mechanism). One barrier + one vmcnt(0)
// per K-tile; depth-1 staging into the opposite buffer (race-free: reads
// of buf completed before barrier; DMA into nbuf drained by vmcnt before
// barrier).
// LDS layout per matrix: [256 rows][32 cols] in 16B chunks, 4 chunks/row,
// physical chunk = logical ^ (row&3)  (verified bank-balanced: 8 lanes per
// 16B-span on every b128 read). No row permutation (full-tile linear stage).
// MODE 0: gemm1 (A=xb, B=W1[e], K=1024, NT=32, epilogue->hs)
// MODE 1: gemm2 (A=hs[e], B=W2[e], K=2048, NT=64, S=8 expert slices,
//                atomicAdd into out)
template <int MODE>
__global__ __launch_bounds__(512, 4) void gemmk(
    const unsigned short* __restrict__ Ag,
    const unsigned short* __restrict__ Bg,
    const float* __restrict__ bias,
    const float* __restrict__ route,
    void* __restrict__ Cout,
    int n0, int ncRows, int ngx) {
  extern __shared__ unsigned short smem[];
  unsigned short* As = smem;           // 2 bufs x 8192 elems (16KB each)
  unsigned short* Bs = smem + 16384;   // 2 bufs x 8192 elems

  // bijective XCD swizzle (nwg % 8 == 0 by construction)
  const int nwg = gridDim.x;
  const int orig = blockIdx.x;
  const int q8 = nwg >> 3;
  const int wg = (orig & 7) * q8 + (orig >> 3);
  const int bx = wg % ngx;
  const int rem = wg / ngx;
  int by, ez;
  if (MODE == 0) { by = rem & 7; ez = rem >> 3; }   // by in [0,8), e in [0,8)
  else           { by = rem & 3; ez = rem >> 2; }   // by in [0,4), e in [0,8)

  const int tid = threadIdx.x;
  const int wid = tid >> 6, lane = tid & 63;
  const int wm = wid >> 2, wn = wid & 3;

  const int KA = (MODE == 0) ? Dd : Hd;  // K extent == row stride of A and B
  const int NT = KA / 32;

  const size_t Abase = (MODE == 0)
      ? (size_t)(n0 + bx * 256) * Dd
      : (size_t)ez * ncRows * Hd + (size_t)(bx * 256) * Hd;
  const size_t Bbase = (MODE == 0)
      ? (size_t)ez * Hd * Dd + (size_t)(by * 256) * Dd
      : (size_t)ez * Od * Hd + (size_t)(by * 256) * Hd;

  // ---- staging addresses (kt-invariant parts precomputed) ----
  // instruction s of wave w covers chunks (s*8+w)*64 + lane; chunk q:
  // row = q>>2, physical chunk = q&3, logical chunk = (q&3) ^ (row&3)
  const int q0 = (0 * 8 + wid) * 64 + lane;
  const int q1 = (1 * 8 + wid) * 64 + lane;
  const int r0s = q0 >> 2, r1s = q1 >> 2;
  const int c0s = (((q0 & 3) ^ (r0s & 3)) * 8);
  const int c1s = (((q1 & 3) ^ (r1s & 3)) * 8);
  const int d0 = (0 * 8 + wid) * 512;  // dest elem offsets (wave-uniform)
  const int d1 = (1 * 8 + wid) * 512;

  auto stage = [&](int buf, int kt) {
    const size_t k0 = (size_t)kt * 32;
    gload16(Ag + Abase + (size_t)r0s * KA + k0 + c0s, &As[buf * 8192 + d0]);
    gload16(Ag + Abase + (size_t)r1s * KA + k0 + c1s, &As[buf * 8192 + d1]);
    gload16(Bg + Bbase + (size_t)r0s * KA + k0 + c0s, &Bs[buf * 8192 + d0]);
    gload16(Bg + Bbase + (size_t)r1s * KA + k0 + c1s, &Bs[buf * 8192 + d1]);
  };

  // ---- fragment read addresses ----
  // lane reads row base + (lane&15), logical chunk lane>>4;
  // row&3 == lane&3 for all frag rows (frag offsets are multiples of 16)
  const int pchunk = ((lane >> 4) ^ (lane & 3)) * 16;  // physical chunk byte
  const int aByte = (wm * 128 + (lane & 15)) * 64 + pchunk;
  const int bByte = (wn * 64 + (lane & 15)) * 64 + pchunk;

  auto rdA = [&](int buf, int mi) -> bf16x8 {
    return *(const bf16x8*)((const char*)As + buf * 16384 + aByte + mi * 1024);
  };
  auto rdB = [&](int buf, int ni) -> bf16x8 {
    return *(const bf16x8*)((const char*)Bs + buf * 16384 + bByte + ni * 1024);
  };

  f32x4 acc[8][4];
  #pragma unroll
  for (int i = 0; i < 8; ++i)
    #pragma unroll
    for (int j = 0; j < 4; ++j) acc[i][j] = (f32x4){0.f, 0.f, 0.f, 0.f};

  // prologue: stage tile0 -> buf0
  stage(0, 0);
  asm volatile("s_waitcnt vmcnt(0)" ::: "memory");
  __builtin_amdgcn_sched_barrier(0);
  __builtin_amdgcn_s_barrier();

  for (int U = 0; U < NT; ++U) {
    const int buf = U & 1;
    if (U + 1 < NT) stage(buf ^ 1, U + 1);
    bf16x8 a[8], b[4];
    #pragma unroll
    for (int mi = 0; mi < 8; ++mi) a[mi] = rdA(buf, mi);
    #pragma unroll
    for (int ni = 0; ni < 4; ++ni) b[ni] = rdB(buf, ni);
    __builtin_amdgcn_s_setprio(1);
    #pragma unroll
    for (int mi = 0; mi < 8; ++mi)
      #pragma unroll
      for (int ni = 0; ni < 4; ++ni)
        acc[mi][ni] = __builtin_amdgcn_mfma_f32_16x16x32_bf16(a[mi], b[ni], acc[mi][ni], 0, 0, 0);
    __builtin_amdgcn_s_setprio(0);
    if (U + 1 < NT) {
      asm volatile("s_waitcnt vmcnt(0)" ::: "memory");
    }
    __builtin_amdgcn_sched_barrier(0);
    __builtin_amdgcn_s_barrier();
  }

  // ---------------- epilogue ----------------
  if (MODE == 0) {
    unsigned short* hs = (unsigned short*)Cout;
    unsigned short* base = hs + (size_t)ez * ((size_t)ncRows * Hd);
    #pragma unroll
    for (int mi = 0; mi < 8; ++mi) {
      const int rowc = bx * 256 + wm * 128 + mi * 16 + (lane >> 4) * 4;
      float rw[4];
      #pragma unroll
      for (int j = 0; j < 4; ++j) rw[j] = route[(size_t)(n0 + rowc + j) * Ed + ez];
      #pragma unroll
      for (int ni = 0; ni < 4; ++ni) {
        const int col = by * 256 + wn * 64 + ni * 16 + (lane & 15);
        const float bv = bias[ez * Hd + col];
        #pragma unroll
        for (int j = 0; j < 4; ++j) {
          float v = acc[mi][ni][j] + bv;
          v = fmaxf(v, 0.f);
          v = v * v * rw[j];
          base[(size_t)(rowc + j) * Hd + col] = f2bf(v);
        }
      }
    }
  } else {
    float* out = (float*)Cout;
    #pragma unroll
    for (int mi = 0; mi < 8; ++mi) {
      const int row = n0 + bx * 256 + wm * 128 + mi * 16 + (lane >> 4) * 4;
      #pragma unroll
      for (int ni = 0; ni < 4; ++ni) {
        const int col = by * 256 + wn * 64 + ni * 16 + (lane & 15);
        #pragma unroll
        for (int j = 0; j < 4; ++j)
          atomicAdd(out + (size_t)(row + j) * Od + col, acc[mi][ni][j]);
      }
    }
  }
}

extern "C" void kernel_launch(void* const* d_in, const int* in_sizes, int n_in,
                              void* d_out, int out_size, void* d_ws, size_t ws_size,
                              hipStream_t stream) {
  const float* x  = (const float*)d_in[0];
  const float* Wr = (const float*)d_in[1];
  const float* br = (const float*)d_in[2];
  const float* W1 = (const float*)d_in[3];
  const float* b1 = (const float*)d_in[4];
  const float* W2 = (const float*)d_in[5];
  const float* b2 = (const float*)d_in[6];
  float* out = (float*)d_out;

  char* ws = (char*)d_ws;
  size_t off = 0;
  float* route = (float*)(ws + off);                 off += (size_t)Nd * Ed * 4;
  unsigned short* xb  = (unsigned short*)(ws + off); off += (size_t)Nd * Dd * 2;
  unsigned short* w1b = (unsigned short*)(ws + off); off += (size_t)Ed * Hd * Dd * 2;
  unsigned short* w2b = (unsigned short*)(ws + off); off += (size_t)Ed * Od * Hd * 2;
  unsigned short* hs  = (unsigned short*)(ws + off);

  size_t remain = (ws_size > off) ? (ws_size - off) : 0;
  const size_t perRow = (size_t)Ed * Hd * 2;  // bytes of hs per token row
  long long ncMax = (long long)(remain / perRow);
  int NC = (int)(ncMax & ~255LL);
  if (NC > Nd) NC = Nd;
  if (NC < 256) NC = 256;

  hipFuncSetAttribute(reinterpret_cast<const void*>(&gemmk<0>),
                      hipFuncAttributeMaxDynamicSharedMemorySize, 65536);
  hipFuncSetAttribute(reinterpret_cast<const void*>(&gemmk<1>),
                      hipFuncAttributeMaxDynamicSharedMemorySize, 65536);

  cvt_kernel<<<2048, 256, 0, stream>>>(W1, w1b, Ed * Hd * Dd / 8);
  cvt_kernel<<<2048, 256, 0, stream>>>(W2, w2b, Ed * Od * Hd / 8);
  router_kernel<<<Nd, 256, 0, stream>>>(x, Wr, br, route, xb);
  init_out_kernel<<<Nd * Od / 256, 256, 0, stream>>>(route, b2, out);

  for (int n0 = 0; n0 < Nd; n0 += NC) {
    int nc = (NC < (Nd - n0)) ? NC : (Nd - n0);
    int ngx = nc / 256;
    gemmk<0><<<ngx * 8 * Ed, 512, 65536, stream>>>(xb, w1b, b1, route, hs, n0, nc, ngx);
    gemmk<1><<<ngx * 4 * Ed, 512, 65536, stream>>>(hs, w2b, nullptr, nullptr, out, n0, nc, ngx);
  }
}

// Round 9
// 409.260 us; speedup vs baseline: 6.0831x; 6.0831x over previous
//
#include <hip/hip_runtime.h>
#include <hip/hip_bf16.h>
#include <stdint.h>

#define Dd 1024
#define Hd 2048
#define Od 1024
#define Ed 8
#define Nd 4096

typedef __bf16 bf16x8 __attribute__((ext_vector_type(8)));
typedef float f32x4 __attribute__((ext_vector_type(4)));

__device__ __forceinline__ void gload16(const void* g, void* l) {
  __builtin_amdgcn_global_load_lds(
      (const __attribute__((address_space(1))) void*)g,
      (__attribute__((address_space(3))) void*)l, 16, 0, 0);
}

__device__ __forceinline__ unsigned short f2bf(float f) {
  __hip_bfloat16 h = __float2bfloat16(f);
  return *reinterpret_cast<unsigned short*>(&h);
}

// ---------- f32 -> bf16 conversion, 8 elems / thread ----------
__global__ void cvt_kernel(const float* __restrict__ in,
                           unsigned short* __restrict__ out, int ngroups) {
  int stride = gridDim.x * blockDim.x;
  for (int g = blockIdx.x * blockDim.x + threadIdx.x; g < ngroups; g += stride) {
    const float4* p = (const float4*)(in + (size_t)g * 8);
    float4 a = p[0], b = p[1];
    unsigned short o[8];
    o[0] = f2bf(a.x); o[1] = f2bf(a.y); o[2] = f2bf(a.z); o[3] = f2bf(a.w);
    o[4] = f2bf(b.x); o[5] = f2bf(b.y); o[6] = f2bf(b.z); o[7] = f2bf(b.w);
    *(int4*)(out + (size_t)g * 8) = *(int4*)o;
  }
}

// ---------- router (also emits xb bf16) ----------
__global__ void router_kernel(const float* __restrict__ x, const float* __restrict__ Wr,
                              const float* __restrict__ br, float* __restrict__ route,
                              unsigned short* __restrict__ xb) {
  const int n = blockIdx.x;
  const int t = threadIdx.x;  // 256
  __shared__ float xs[Dd];
  float4 v = *(const float4*)&x[(size_t)n * Dd + t * 4];
  *(float4*)&xs[t * 4] = v;
  unsigned short o[4] = {f2bf(v.x), f2bf(v.y), f2bf(v.z), f2bf(v.w)};
  *(uint2*)&xb[(size_t)n * Dd + t * 4] = *(const uint2*)o;
  __syncthreads();
  float p[Ed];
  #pragma unroll
  for (int e = 0; e < Ed; ++e) p[e] = 0.f;
  for (int d = t; d < Dd; d += 256) {
    float xv = xs[d];
    #pragma unroll
    for (int e = 0; e < Ed; ++e) p[e] += xv * Wr[e * Dd + d];
  }
  __shared__ float red[Ed][4];
  const int lane = t & 63, wid = t >> 6;
  #pragma unroll
  for (int e = 0; e < Ed; ++e) {
    float vv = p[e];
    for (int off = 32; off > 0; off >>= 1) vv += __shfl_down(vv, off);
    if (lane == 0) red[e][wid] = vv;
  }
  __syncthreads();
  if (t == 0) {
    float lg[Ed], mx = -1e30f;
    #pragma unroll
    for (int e = 0; e < Ed; ++e) {
      lg[e] = red[e][0] + red[e][1] + red[e][2] + red[e][3] + br[e];
      mx = fmaxf(mx, lg[e]);
    }
    float s = 0.f;
    #pragma unroll
    for (int e = 0; e < Ed; ++e) { lg[e] = expf(lg[e] - mx); s += lg[e]; }
    float inv = 1.f / s;
    #pragma unroll
    for (int e = 0; e < Ed; ++e) route[(size_t)n * Ed + e] = lg[e] * inv;
  }
}

// ---------- out init: out[n,o] = sum_e route[n,e] * b2[e,o] ----------
__global__ void init_out_kernel(const float* __restrict__ route, const float* __restrict__ b2,
                                float* __restrict__ out) {
  const int idx = blockIdx.x * 256 + threadIdx.x;
  const int n = idx >> 10, o = idx & (Od - 1);
  float s = 0.f;
  #pragma unroll
  for (int e = 0; e < Ed; ++e) s += route[(size_t)n * Ed + e] * b2[e * Od + o];
  out[idx] = s;
}

// ============ 128x128 BK=64 GEMM, 32KB LDS single-buf, 3 blocks/CU ==========
// m97 replica (874-912 TF measured in learn_hip at this geometry/occupancy):
// the latency-hiding engine is CROSS-BLOCK overlap at 12 waves/CU, not
// schedule engineering. Per K-tile:
//   [loop top] vmcnt(0)+sched_barrier+s_barrier  -> tile kt resident
//   read 16 ds_read_b128 frags into regs
//   __syncthreads()                              -> all reads drained
//   stage(kt+1) (8 gload16, same buffer)         -> DMA overlapped by...
//   32 MFMA on regs (independent of DMA)
// LDS per matrix [128 rows][8 chunks of 16B]; physical chunk = logical ^
// (row&7) (R2-proven 0-conflict pattern), staged via inverse-swizzled
// global source + linear LDS dest (rule 21).
// MODE 0: gemm1 A=xb B=W1[e] K=1024, epilogue squared-relu*route -> hs bf16
// MODE 1: gemm2 A=hs[e] B=W2[e], z-pair K=2*2048, atomicAdd -> out
template <int MODE>
__global__ __launch_bounds__(256, 3) void gemm128(
    const unsigned short* __restrict__ Ag,
    const unsigned short* __restrict__ Bg,
    const float* __restrict__ bias,
    const float* __restrict__ route,
    void* __restrict__ Cout,
    int n0, int ncRows, int ngx) {
  __shared__ __align__(16) unsigned short As[128 * 64];
  __shared__ __align__(16) unsigned short Bs[128 * 64];

  // bijective XCD swizzle (nwg % 8 == 0 by construction)
  const int nwg = gridDim.x;
  const int orig = blockIdx.x;
  const int q8 = nwg >> 3;
  const int wg = (orig & 7) * q8 + (orig >> 3);
  const int bx = wg % ngx;
  const int rem = wg / ngx;
  int by, ez;
  if (MODE == 0) { by = rem & 15; ez = rem >> 4; }  // by in [0,16), e in [0,8)
  else           { by = rem & 7;  ez = rem >> 3; }  // by in [0,8),  z in [0,4)

  const int tid = threadIdx.x;
  const int wid = tid >> 6, lane = tid & 63;
  const int wm = wid >> 1, wn = wid & 1;

  const int KA = (MODE == 0) ? Dd : Hd;   // row stride of A and B
  const int NT = (MODE == 0) ? (Dd / 64) : (2 * Hd / 64);

  const size_t Abase = (MODE == 0)
      ? (size_t)(n0 + bx * 128) * Dd
      : (size_t)(bx * 128) * Hd;          // + e*ncRows*Hd added per kt
  const size_t Bbase = (MODE == 0)
      ? (size_t)ez * Hd * Dd + (size_t)(by * 128) * Dd
      : (size_t)(by * 128) * Hd;          // + e*Od*Hd added per kt

  // staging: 4 rounds per matrix; round i covers chunks q = i*256 + tid
  // q: row = q>>3, phys chunk = q&7, logical chunk = (q&7)^(row&7)
  int srow[4], scol[4], sdst[4];
  #pragma unroll
  for (int i = 0; i < 4; ++i) {
    const int q = i * 256 + tid;
    srow[i] = q >> 3;
    scol[i] = ((q & 7) ^ (srow[i] & 7)) * 8;
    sdst[i] = q * 8;  // elem offset in LDS
  }

  auto stage = [&](int kt) {
    size_t Ab, Bb;
    int k0;
    if (MODE == 0) {
      Ab = Abase; Bb = Bbase; k0 = kt * 64;
    } else {
      const int e = ez * 2 + (kt >> 5);
      Ab = Abase + (size_t)e * ncRows * Hd;
      Bb = Bbase + (size_t)e * Od * Hd;
      k0 = (kt & 31) * 64;
    }
    #pragma unroll
    for (int i = 0; i < 4; ++i)
      gload16(Ag + Ab + (size_t)srow[i] * KA + k0 + scol[i], &As[sdst[i]]);
    #pragma unroll
    for (int i = 0; i < 4; ++i)
      gload16(Bg + Bb + (size_t)srow[i] * KA + k0 + scol[i], &Bs[sdst[i]]);
  };

  // fragment reads: lane reads row base+(lane&15); logical chunk kk*4+(lane>>4)
  // phys chunk = logical ^ (lane&7)  (row&7 == lane&7 for these rows)
  const int pchunk0 = ((lane >> 4) ^ (lane & 7)) * 16;       // kk=0 byte
  const int pchunk1 = ((4 + (lane >> 4)) ^ (lane & 7)) * 16; // kk=1 byte
  const int aRow = (wm * 64 + (lane & 15)) * 128;            // byte
  const int bRow = (wn * 64 + (lane & 15)) * 128;

  f32x4 acc[4][4];
  #pragma unroll
  for (int i = 0; i < 4; ++i)
    #pragma unroll
    for (int j = 0; j < 4; ++j) acc[i][j] = (f32x4){0.f, 0.f, 0.f, 0.f};

  stage(0);

  for (int kt = 0; kt < NT; ++kt) {
    asm volatile("s_waitcnt vmcnt(0)" ::: "memory");
    __builtin_amdgcn_sched_barrier(0);
    __builtin_amdgcn_s_barrier();
    bf16x8 a[4][2], b[4][2];
    #pragma unroll
    for (int mi = 0; mi < 4; ++mi) {
      a[mi][0] = *(const bf16x8*)((const char*)As + aRow + mi * 2048 + pchunk0);
      a[mi][1] = *(const bf16x8*)((const char*)As + aRow + mi * 2048 + pchunk1);
    }
    #pragma unroll
    for (int ni = 0; ni < 4; ++ni) {
      b[ni][0] = *(const bf16x8*)((const char*)Bs + bRow + ni * 2048 + pchunk0);
      b[ni][1] = *(const bf16x8*)((const char*)Bs + bRow + ni * 2048 + pchunk1);
    }
    __syncthreads();           // all waves' reads drained; buffer reusable
    if (kt + 1 < NT) stage(kt + 1);   // DMA hidden under MFMA below
    __builtin_amdgcn_s_setprio(1);
    #pragma unroll
    for (int kk = 0; kk < 2; ++kk)
      #pragma unroll
      for (int mi = 0; mi < 4; ++mi)
        #pragma unroll
        for (int ni = 0; ni < 4; ++ni)
          acc[mi][ni] = __builtin_amdgcn_mfma_f32_16x16x32_bf16(a[mi][kk], b[ni][kk], acc[mi][ni], 0, 0, 0);
    __builtin_amdgcn_s_setprio(0);
  }

  // ---------------- epilogue ----------------
  if (MODE == 0) {
    unsigned short* hs = (unsigned short*)Cout;
    unsigned short* base = hs + (size_t)ez * ((size_t)ncRows * Hd);
    #pragma unroll
    for (int mi = 0; mi < 4; ++mi) {
      const int rowc = bx * 128 + wm * 64 + mi * 16 + (lane >> 4) * 4;
      float rw[4];
      #pragma unroll
      for (int j = 0; j < 4; ++j) rw[j] = route[(size_t)(n0 + rowc + j) * Ed + ez];
      #pragma unroll
      for (int ni = 0; ni < 4; ++ni) {
        const int col = by * 128 + wn * 64 + ni * 16 + (lane & 15);
        const float bv = bias[ez * Hd + col];
        #pragma unroll
        for (int j = 0; j < 4; ++j) {
          float v = acc[mi][ni][j] + bv;
          v = fmaxf(v, 0.f);
          v = v * v * rw[j];
          base[(size_t)(rowc + j) * Hd + col] = f2bf(v);
        }
      }
    }
  } else {
    float* out = (float*)Cout;
    #pragma unroll
    for (int mi = 0; mi < 4; ++mi) {
      const int row = n0 + bx * 128 + wm * 64 + mi * 16 + (lane >> 4) * 4;
      #pragma unroll
      for (int ni = 0; ni < 4; ++ni) {
        const int col = by * 128 + wn * 64 + ni * 16 + (lane & 15);
        #pragma unroll
        for (int j = 0; j < 4; ++j)
          atomicAdd(out + (size_t)(row + j) * Od + col, acc[mi][ni][j]);
      }
    }
  }
}

extern "C" void kernel_launch(void* const* d_in, const int* in_sizes, int n_in,
                              void* d_out, int out_size, void* d_ws, size_t ws_size,
                              hipStream_t stream) {
  const float* x  = (const float*)d_in[0];
  const float* Wr = (const float*)d_in[1];
  const float* br = (const float*)d_in[2];
  const float* W1 = (const float*)d_in[3];
  const float* b1 = (const float*)d_in[4];
  const float* W2 = (const float*)d_in[5];
  const float* b2 = (const float*)d_in[6];
  float* out = (float*)d_out;

  char* ws = (char*)d_ws;
  size_t off = 0;
  float* route = (float*)(ws + off);                 off += (size_t)Nd * Ed * 4;
  unsigned short* xb  = (unsigned short*)(ws + off); off += (size_t)Nd * Dd * 2;
  unsigned short* w1b = (unsigned short*)(ws + off); off += (size_t)Ed * Hd * Dd * 2;
  unsigned short* w2b = (unsigned short*)(ws + off); off += (size_t)Ed * Od * Hd * 2;
  unsigned short* hs  = (unsigned short*)(ws + off);

  size_t remain = (ws_size > off) ? (ws_size - off) : 0;
  const size_t perRow = (size_t)Ed * Hd * 2;  // bytes of hs per token row
  long long ncMax = (long long)(remain / perRow);
  int NC = (int)(ncMax & ~127LL);
  if (NC > Nd) NC = Nd;
  if (NC < 128) NC = 128;

  cvt_kernel<<<2048, 256, 0, stream>>>(W1, w1b, Ed * Hd * Dd / 8);
  cvt_kernel<<<2048, 256, 0, stream>>>(W2, w2b, Ed * Od * Hd / 8);
  router_kernel<<<Nd, 256, 0, stream>>>(x, Wr, br, route, xb);
  init_out_kernel<<<Nd * Od / 256, 256, 0, stream>>>(route, b2, out);

  for (int n0 = 0; n0 < Nd; n0 += NC) {
    int nc = (NC < (Nd - n0)) ? NC : (Nd - n0);
    int ngx = nc / 128;
    gemm128<0><<<ngx * 16 * Ed, 256, 0, stream>>>(xb, w1b, b1, route, hs, n0, nc, ngx);
    gemm128<1><<<ngx * 8 * 4, 256, 0, stream>>>(hs, w2b, nullptr, nullptr, out, n0, nc, ngx);
  }
}

// Round 11
// 383.750 us; speedup vs baseline: 6.4875x; 1.0665x over previous
//
#include <hip/hip_runtime.h>
#include <hip/hip_bf16.h>
#include <stdint.h>

#define Dd 1024
#define Hd 2048
#define Od 1024
#define Ed 8
#define Nd 4096

typedef __bf16 bf16x8 __attribute__((ext_vector_type(8)));
typedef float f32x4 __attribute__((ext_vector_type(4)));
typedef int i32x4 __attribute__((ext_vector_type(4)));

__device__ __forceinline__ void gload16(const void* g, void* l) {
  __builtin_amdgcn_global_load_lds(
      (const __attribute__((address_space(1))) void*)g,
      (__attribute__((address_space(3))) void*)l, 16, 0, 0);
}

__device__ __forceinline__ unsigned short f2bf(float f) {
  __hip_bfloat16 h = __float2bfloat16(f);
  return *reinterpret_cast<unsigned short*>(&h);
}

__device__ __forceinline__ float blockMax256(float v) {
  __shared__ float sm[4];
  #pragma unroll
  for (int o = 32; o > 0; o >>= 1) v = fmaxf(v, __shfl_down(v, o));
  const int lane = threadIdx.x & 63, w = threadIdx.x >> 6;
  if (lane == 0) sm[w] = v;
  __syncthreads();
  return fmaxf(fmaxf(sm[0], sm[1]), fmaxf(sm[2], sm[3]));
}

// ---------- per-row f32 -> i8 quantization (row-max scaling) ----------
template <int K>
__global__ void qrow_kernel(const float* __restrict__ in,
                            signed char* __restrict__ out,
                            float* __restrict__ scale) {
  const int row = blockIdx.x;
  const int t = threadIdx.x;  // 256
  const float* r = in + (size_t)row * K;
  float v[K / 256];
  float m = 0.f;
  #pragma unroll
  for (int i = 0; i < K / 256; ++i) {
    v[i] = r[t + i * 256];
    m = fmaxf(m, fabsf(v[i]));
  }
  const float M = blockMax256(m);
  const float inv = (M > 0.f) ? 127.f / M : 0.f;
  signed char* o = out + (size_t)row * K;
  #pragma unroll
  for (int i = 0; i < K / 256; ++i)
    o[t + i * 256] = (signed char)__float2int_rn(v[i] * inv);
  if (t == 0) scale[row] = M / 127.f;
}

// ---------- f32 -> bf16 conversion, 8 elems / thread ----------
__global__ void cvt_kernel(const float* __restrict__ in,
                           unsigned short* __restrict__ out, int ngroups) {
  int stride = gridDim.x * blockDim.x;
  for (int g = blockIdx.x * blockDim.x + threadIdx.x; g < ngroups; g += stride) {
    const float4* p = (const float4*)(in + (size_t)g * 8);
    float4 a = p[0], b = p[1];
    unsigned short o[8];
    o[0] = f2bf(a.x); o[1] = f2bf(a.y); o[2] = f2bf(a.z); o[3] = f2bf(a.w);
    o[4] = f2bf(b.x); o[5] = f2bf(b.y); o[6] = f2bf(b.z); o[7] = f2bf(b.w);
    *(int4*)(out + (size_t)g * 8) = *(int4*)o;
  }
}

// ---------- router (f32, exact) ----------
__global__ void router_kernel(const float* __restrict__ x, const float* __restrict__ Wr,
                              const float* __restrict__ br, float* __restrict__ route) {
  const int n = blockIdx.x;
  const int t = threadIdx.x;  // 256
  __shared__ float xs[Dd];
  float4 v = *(const float4*)&x[(size_t)n * Dd + t * 4];
  *(float4*)&xs[t * 4] = v;
  __syncthreads();
  float p[Ed];
  #pragma unroll
  for (int e = 0; e < Ed; ++e) p[e] = 0.f;
  for (int d = t; d < Dd; d += 256) {
    float xv = xs[d];
    #pragma unroll
    for (int e = 0; e < Ed; ++e) p[e] += xv * Wr[e * Dd + d];
  }
  __shared__ float red[Ed][4];
  const int lane = t & 63, wid = t >> 6;
  #pragma unroll
  for (int e = 0; e < Ed; ++e) {
    float vv = p[e];
    for (int off = 32; off > 0; off >>= 1) vv += __shfl_down(vv, off);
    if (lane == 0) red[e][wid] = vv;
  }
  __syncthreads();
  if (t == 0) {
    float lg[Ed], mx = -1e30f;
    #pragma unroll
    for (int e = 0; e < Ed; ++e) {
      lg[e] = red[e][0] + red[e][1] + red[e][2] + red[e][3] + br[e];
      mx = fmaxf(mx, lg[e]);
    }
    float s = 0.f;
    #pragma unroll
    for (int e = 0; e < Ed; ++e) { lg[e] = expf(lg[e] - mx); s += lg[e]; }
    float inv = 1.f / s;
    #pragma unroll
    for (int e = 0; e < Ed; ++e) route[(size_t)n * Ed + e] = lg[e] * inv;
  }
}

// ---------- out init: out[n,o] = sum_e route[n,e] * b2[e,o] ----------
__global__ void init_out_kernel(const float* __restrict__ route, const float* __restrict__ b2,
                                float* __restrict__ out) {
  const int idx = blockIdx.x * 256 + threadIdx.x;
  const int n = idx >> 10, o = idx & (Od - 1);
  float s = 0.f;
  #pragma unroll
  for (int e = 0; e < Ed; ++e) s += route[(size_t)n * Ed + e] * b2[e * Od + o];
  out[idx] = s;
}

// ============ GEMM1: i8 256x256, BK=128 B, whole-tile schedule ============
// A=xq[n][D] i8, B=w1q[e][h][D] i8, K=1024, NT=8.
// Epilogue: f = i32*sx[n]*sw1[e,col] + b1 -> relu^2 * route -> hs bf16.
__global__ __launch_bounds__(512, 2) void gemmq1(
    const signed char* __restrict__ Ag,
    const signed char* __restrict__ Bg,
    const float* __restrict__ bias,
    const float* __restrict__ route,
    const float* __restrict__ sA,
    const float* __restrict__ sB,
    unsigned short* __restrict__ hs,
    int n0, int ncRows, int ngx) {
  extern __shared__ char smem[];
  char* As = smem;            // 2 bufs x 32768 B
  char* Bs = smem + 65536;

  const int nwg = gridDim.x;
  const int orig = blockIdx.x;
  const int q8 = nwg >> 3;
  const int wg = (orig & 7) * q8 + (orig >> 3);
  const int bx = wg % ngx;
  const int rem = wg / ngx;
  const int by = rem & 7, ez = rem >> 3;

  const int tid = threadIdx.x;
  const int wid = tid >> 6, lane = tid & 63;
  const int wm = wid >> 2, wn = wid & 3;

  const int KB = Dd;  // bytes/row
  const int NT = KB / 128;

  const signed char* Abase = Ag + (size_t)(n0 + bx * 256) * Dd;
  const signed char* Bbase = Bg + (size_t)ez * Hd * Dd + (size_t)(by * 256) * Dd;

  const int trow = tid >> 3;
  const int tcs = ((tid & 7) ^ (trow & 7)) * 16;

  auto stageA = [&](int buf, int kt, int mh) {
    #pragma unroll
    for (int s = 0; s < 2; ++s) {
      const int pa = mh * 128 + s * 64 + trow;
      const int m = ((pa >> 6) & 1) * 128 + ((pa >> 7) & 1) * 64 + (pa & 63);
      gload16(Abase + (size_t)m * KB + kt * 128 + tcs,
              &As[buf * 32768 + (mh * 128 + s * 64) * 128 + wid * 1024]);
    }
  };
  auto stageB = [&](int buf, int kt, int nh) {
    #pragma unroll
    for (int s = 0; s < 2; ++s) {
      const int pb = nh * 128 + s * 64 + trow;
      const int n = ((pb >> 5) & 3) * 64 + ((pb >> 7) & 1) * 32 + (pb & 31);
      gload16(Bbase + (size_t)n * KB + kt * 128 + tcs,
              &Bs[buf * 32768 + (nh * 128 + s * 64) * 128 + wid * 1024]);
    }
  };

  const int laneRow = lane & 15;
  const int swz[2] = { ((lane >> 4) ^ (lane & 7)) * 16,
                       ((4 + (lane >> 4)) ^ (lane & 7)) * 16 };
  const int aRowB = (wm * 64 + laneRow) * 128;
  const int bRowB = (wn * 32 + laneRow) * 128;

  auto rdA = [&](int buf, int mh, int mi, int kk) -> i32x4 {
    return *(const i32x4*)(As + buf * 32768 + aRowB + (mh * 128 + mi * 16) * 128 + swz[kk]);
  };
  auto rdB = [&](int buf, int nh, int ni, int kk) -> i32x4 {
    return *(const i32x4*)(Bs + buf * 32768 + bRowB + (nh * 128 + ni * 16) * 128 + swz[kk]);
  };

  i32x4 acc[8][4];
  #pragma unroll
  for (int i = 0; i < 8; ++i)
    #pragma unroll
    for (int j = 0; j < 4; ++j) acc[i][j] = (i32x4){0, 0, 0, 0};
  i32x4 a0[4][2], a1[4][2], b0[2][2], b1[2][2];

  stageA(0, 0, 0); stageB(0, 0, 0); stageA(0, 0, 1); stageB(0, 0, 1);
  asm volatile("s_waitcnt vmcnt(0)" ::: "memory");
  __builtin_amdgcn_sched_barrier(0);
  __builtin_amdgcn_s_barrier();

  for (int U = 0; U < NT; ++U) {
    const int buf = U & 1;
    if (U + 1 < NT) {
      stageA(buf ^ 1, U + 1, 0); stageB(buf ^ 1, U + 1, 0);
      stageA(buf ^ 1, U + 1, 1); stageB(buf ^ 1, U + 1, 1);
    }
    #pragma unroll
    for (int mi = 0; mi < 4; ++mi) { a0[mi][0] = rdA(buf, 0, mi, 0); a0[mi][1] = rdA(buf, 0, mi, 1); }
    #pragma unroll
    for (int ni = 0; ni < 2; ++ni) { b0[ni][0] = rdB(buf, 0, ni, 0); b0[ni][1] = rdB(buf, 0, ni, 1); }
    __builtin_amdgcn_s_setprio(1);
    #pragma unroll
    for (int kk = 0; kk < 2; ++kk)
      #pragma unroll
      for (int mi = 0; mi < 4; ++mi)
        #pragma unroll
        for (int ni = 0; ni < 2; ++ni)
          acc[mi][ni] = __builtin_amdgcn_mfma_i32_16x16x64_i8(a0[mi][kk], b0[ni][kk], acc[mi][ni], 0, 0, 0);
    __builtin_amdgcn_s_setprio(0);
    #pragma unroll
    for (int mi = 0; mi < 4; ++mi) { a1[mi][0] = rdA(buf, 1, mi, 0); a1[mi][1] = rdA(buf, 1, mi, 1); }
    __builtin_amdgcn_s_setprio(1);
    #pragma unroll
    for (int kk = 0; kk < 2; ++kk)
      #pragma unroll
      for (int mi = 0; mi < 4; ++mi)
        #pragma unroll
        for (int ni = 0; ni < 2; ++ni)
          acc[4 + mi][ni] = __builtin_amdgcn_mfma_i32_16x16x64_i8(a1[mi][kk], b0[ni][kk], acc[4 + mi][ni], 0, 0, 0);
    __builtin_amdgcn_s_setprio(0);
    #pragma unroll
    for (int ni = 0; ni < 2; ++ni) { b1[ni][0] = rdB(buf, 1, ni, 0); b1[ni][1] = rdB(buf, 1, ni, 1); }
    __builtin_amdgcn_s_setprio(1);
    #pragma unroll
    for (int kk = 0; kk < 2; ++kk)
      #pragma unroll
      for (int mi = 0; mi < 4; ++mi)
        #pragma unroll
        for (int ni = 0; ni < 2; ++ni)
          acc[4 + mi][2 + ni] = __builtin_amdgcn_mfma_i32_16x16x64_i8(a1[mi][kk], b1[ni][kk], acc[4 + mi][2 + ni], 0, 0, 0);
    __builtin_amdgcn_s_setprio(0);
    __builtin_amdgcn_s_setprio(1);
    #pragma unroll
    for (int kk = 0; kk < 2; ++kk)
      #pragma unroll
      for (int mi = 0; mi < 4; ++mi)
        #pragma unroll
        for (int ni = 0; ni < 2; ++ni)
          acc[mi][2 + ni] = __builtin_amdgcn_mfma_i32_16x16x64_i8(a0[mi][kk], b1[ni][kk], acc[mi][2 + ni], 0, 0, 0);
    __builtin_amdgcn_s_setprio(0);
    if (U + 1 < NT) {
      asm volatile("s_waitcnt vmcnt(0)" ::: "memory");
    }
    __builtin_amdgcn_sched_barrier(0);
    __builtin_amdgcn_s_barrier();
  }

  unsigned short* base = hs + (size_t)ez * ((size_t)ncRows * Hd);
  #pragma unroll
  for (int M = 0; M < 8; ++M) {
    const int mh = M >> 2, mi = M & 3;
    const int rowc = bx * 256 + wm * 128 + mh * 64 + mi * 16 + (lane >> 4) * 4;
    float sx4[4], rw[4];
    #pragma unroll
    for (int j = 0; j < 4; ++j) {
      sx4[j] = sA[n0 + rowc + j];
      rw[j] = route[(size_t)(n0 + rowc + j) * Ed + ez];
    }
    #pragma unroll
    for (int N = 0; N < 4; ++N) {
      const int nh = N >> 1, ni = N & 1;
      const int col = by * 256 + wn * 64 + nh * 32 + ni * 16 + (lane & 15);
      const float sw = sB[ez * Hd + col];
      const float bv = bias[ez * Hd + col];
      #pragma unroll
      for (int j = 0; j < 4; ++j) {
        float v = (float)acc[M][N][j] * (sx4[j] * sw) + bv;
        v = fmaxf(v, 0.f);
        v = v * v * rw[j];
        base[(size_t)(rowc + j) * Hd + col] = f2bf(v);
      }
    }
  }
}

// ============ GEMM2: bf16 256x256, single-expert, whole-tile schedule =======
// A=hs[e][n][H] bf16, B=w2b[e][o][H] bf16, K=2048, NT=32; atomicAdd -> out.
__global__ __launch_bounds__(512, 2) void gemm2b(
    const unsigned short* __restrict__ Ag,
    const unsigned short* __restrict__ Bg,
    float* __restrict__ out,
    int n0, int ncRows, int ngx) {
  extern __shared__ char smemc[];
  unsigned short* As = (unsigned short*)smemc;          // 2 x 16384 elems
  unsigned short* Bs = (unsigned short*)(smemc + 65536);

  const int nwg = gridDim.x;
  const int orig = blockIdx.x;
  const int q8 = nwg >> 3;
  const int wg = (orig & 7) * q8 + (orig >> 3);
  const int bx = wg % ngx;
  const int rem = wg / ngx;
  const int by = rem & 3, ez = rem >> 2;

  const int tid = threadIdx.x;
  const int wid = tid >> 6, lane = tid & 63;
  const int wm = wid >> 2, wn = wid & 3;

  const int NT = Hd / 64;

  const unsigned short* Abase = Ag + (size_t)ez * ncRows * Hd + (size_t)(bx * 256) * Hd;
  const unsigned short* Bbase = Bg + (size_t)ez * Od * Hd + (size_t)(by * 256) * Hd;

  const int trow = tid >> 3;
  const int tcs = ((tid & 7) ^ (trow & 7)) * 8;   // elems

  auto stageA = [&](int buf, int kt, int mh) {
    #pragma unroll
    for (int s = 0; s < 2; ++s) {
      const int pa = mh * 128 + s * 64 + trow;
      const int m = ((pa >> 6) & 1) * 128 + ((pa >> 7) & 1) * 64 + (pa & 63);
      gload16(Abase + (size_t)m * Hd + kt * 64 + tcs,
              &As[(size_t)buf * 16384 + (size_t)(mh * 128 + s * 64) * 64 + wid * 512]);
    }
  };
  auto stageB = [&](int buf, int kt, int nh) {
    #pragma unroll
    for (int s = 0; s < 2; ++s) {
      const int pb = nh * 128 + s * 64 + trow;
      const int n = ((pb >> 5) & 3) * 64 + ((pb >> 7) & 1) * 32 + (pb & 31);
      gload16(Bbase + (size_t)n * Hd + kt * 64 + tcs,
              &Bs[(size_t)buf * 16384 + (size_t)(nh * 128 + s * 64) * 64 + wid * 512]);
    }
  };

  const int laneRow = lane & 15;
  const int swzc[2] = { ((lane >> 4) ^ (lane & 7)) << 3,
                        (((lane >> 4) + 4) ^ (lane & 7)) << 3 };
  const int aRowBase = (wm * 64 + laneRow) * 64;
  const int bRowBase = (wn * 32 + laneRow) * 64;

  auto rdA = [&](int buf, int mh, int mi, int kk) -> bf16x8 {
    return *(const bf16x8*)&As[buf * 16384 + aRowBase + (mh * 128 + mi * 16) * 64 + swzc[kk]];
  };
  auto rdB = [&](int buf, int nh, int ni, int kk) -> bf16x8 {
    return *(const bf16x8*)&Bs[buf * 16384 + bRowBase + (nh * 128 + ni * 16) * 64 + swzc[kk]];
  };

  f32x4 acc[8][4];
  #pragma unroll
  for (int i = 0; i < 8; ++i)
    #pragma unroll
    for (int j = 0; j < 4; ++j) acc[i][j] = (f32x4){0.f, 0.f, 0.f, 0.f};
  bf16x8 a0[4][2], a1[4][2], b0[2][2], b1[2][2];

  stageA(0, 0, 0); stageB(0, 0, 0); stageA(0, 0, 1); stageB(0, 0, 1);
  asm volatile("s_waitcnt vmcnt(0)" ::: "memory");
  __builtin_amdgcn_sched_barrier(0);
  __builtin_amdgcn_s_barrier();

  for (int U = 0; U < NT; ++U) {
    const int buf = U & 1;
    if (U + 1 < NT) {
      stageA(buf ^ 1, U + 1, 0); stageB(buf ^ 1, U + 1, 0);
      stageA(buf ^ 1, U + 1, 1); stageB(buf ^ 1, U + 1, 1);
    }
    #pragma unroll
    for (int mi = 0; mi < 4; ++mi) { a0[mi][0] = rdA(buf, 0, mi, 0); a0[mi][1] = rdA(buf, 0, mi, 1); }
    #pragma unroll
    for (int ni = 0; ni < 2; ++ni) { b0[ni][0] = rdB(buf, 0, ni, 0); b0[ni][1] = rdB(buf, 0, ni, 1); }
    __builtin_amdgcn_s_setprio(1);
    #pragma unroll
    for (int kk = 0; kk < 2; ++kk)
      #pragma unroll
      for (int mi = 0; mi < 4; ++mi)
        #pragma unroll
        for (int ni = 0; ni < 2; ++ni)
          acc[mi][ni] = __builtin_amdgcn_mfma_f32_16x16x32_bf16(a0[mi][kk], b0[ni][kk], acc[mi][ni], 0, 0, 0);
    __builtin_amdgcn_s_setprio(0);
    #pragma unroll
    for (int mi = 0; mi < 4; ++mi) { a1[mi][0] = rdA(buf, 1, mi, 0); a1[mi][1] = rdA(buf, 1, mi, 1); }
    __builtin_amdgcn_s_setprio(1);
    #pragma unroll
    for (int kk = 0; kk < 2; ++kk)
      #pragma unroll
      for (int mi = 0; mi < 4; ++mi)
        #pragma unroll
        for (int ni = 0; ni < 2; ++ni)
          acc[4 + mi][ni] = __builtin_amdgcn_mfma_f32_16x16x32_bf16(a1[mi][kk], b0[ni][kk], acc[4 + mi][ni], 0, 0, 0);
    __builtin_amdgcn_s_setprio(0);
    #pragma unroll
    for (int ni = 0; ni < 2; ++ni) { b1[ni][0] = rdB(buf, 1, ni, 0); b1[ni][1] = rdB(buf, 1, ni, 1); }
    __builtin_amdgcn_s_setprio(1);
    #pragma unroll
    for (int kk = 0; kk < 2; ++kk)
      #pragma unroll
      for (int mi = 0; mi < 4; ++mi)
        #pragma unroll
        for (int ni = 0; ni < 2; ++ni)
          acc[4 + mi][2 + ni] = __builtin_amdgcn_mfma_f32_16x16x32_bf16(a1[mi][kk], b1[ni][kk], acc[4 + mi][2 + ni], 0, 0, 0);
    __builtin_amdgcn_s_setprio(0);
    __builtin_amdgcn_s_setprio(1);
    #pragma unroll
    for (int kk = 0; kk < 2; ++kk)
      #pragma unroll
      for (int mi = 0; mi < 4; ++mi)
        #pragma unroll
        for (int ni = 0; ni < 2; ++ni)
          acc[mi][2 + ni] = __builtin_amdgcn_mfma_f32_16x16x32_bf16(a0[mi][kk], b1[ni][kk], acc[mi][2 + ni], 0, 0, 0);
    __builtin_amdgcn_s_setprio(0);
    if (U + 1 < NT) {
      asm volatile("s_waitcnt vmcnt(0)" ::: "memory");
    }
    __builtin_amdgcn_sched_barrier(0);
    __builtin_amdgcn_s_barrier();
  }

  #pragma unroll
  for (int M = 0; M < 8; ++M) {
    const int mh = M >> 2, mi = M & 3;
    const int row = n0 + bx * 256 + wm * 128 + mh * 64 + mi * 16 + (lane >> 4) * 4;
    #pragma unroll
    for (int N = 0; N < 4; ++N) {
      const int nh = N >> 1, ni = N & 1;
      const int col = by * 256 + wn * 64 + nh * 32 + ni * 16 + (lane & 15);
      #pragma unroll
      for (int j = 0; j < 4; ++j)
        atomicAdd(out + (size_t)(row + j) * Od + col, acc[M][N][j]);
    }
  }
}

extern "C" void kernel_launch(void* const* d_in, const int* in_sizes, int n_in,
                              void* d_out, int out_size, void* d_ws, size_t ws_size,
                              hipStream_t stream) {
  const float* x  = (const float*)d_in[0];
  const float* Wr = (const float*)d_in[1];
  const float* br = (const float*)d_in[2];
  const float* W1 = (const float*)d_in[3];
  const float* b1 = (const float*)d_in[4];
  const float* W2 = (const float*)d_in[5];
  const float* b2 = (const float*)d_in[6];
  float* out = (float*)d_out;

  char* ws = (char*)d_ws;
  size_t off = 0;
  auto alloc = [&](size_t bytes) { char* p = ws + off; off += (bytes + 255) & ~255ULL; return p; };
  float* route = (float*)alloc((size_t)Nd * Ed * 4);
  float* sx    = (float*)alloc((size_t)Nd * 4);
  float* sw1   = (float*)alloc((size_t)Ed * Hd * 4);
  signed char* xq  = (signed char*)alloc((size_t)Nd * Dd);
  signed char* w1q = (signed char*)alloc((size_t)Ed * Hd * Dd);
  unsigned short* w2b = (unsigned short*)alloc((size_t)Ed * Od * Hd * 2);
  unsigned short* hs = (unsigned short*)(ws + off);

  size_t remain = (ws_size > off) ? (ws_size - off) : 0;
  const size_t perRow = (size_t)Ed * Hd * 2;  // bytes of hs per token row
  long long ncMax = (long long)(remain / perRow);
  int NC = (int)(ncMax & ~255LL);
  if (NC > Nd) NC = Nd;
  if (NC < 256) NC = 256;

  hipFuncSetAttribute(reinterpret_cast<const void*>(&gemmq1),
                      hipFuncAttributeMaxDynamicSharedMemorySize, 131072);
  hipFuncSetAttribute(reinterpret_cast<const void*>(&gemm2b),
                      hipFuncAttributeMaxDynamicSharedMemorySize, 131072);

  qrow_kernel<Dd><<<Nd, 256, 0, stream>>>(x, xq, sx);
  qrow_kernel<Dd><<<Ed * Hd, 256, 0, stream>>>(W1, w1q, sw1);
  cvt_kernel<<<2048, 256, 0, stream>>>(W2, w2b, Ed * Od * Hd / 8);
  router_kernel<<<Nd, 256, 0, stream>>>(x, Wr, br, route);
  init_out_kernel<<<Nd * Od / 256, 256, 0, stream>>>(route, b2, out);

  for (int n0 = 0; n0 < Nd; n0 += NC) {
    int nc = (NC < (Nd - n0)) ? NC : (Nd - n0);
    int ngx = nc / 256;
    gemmq1<<<ngx * 8 * Ed, 512, 131072, stream>>>(
        xq, w1q, b1, route, sx, sw1, hs, n0, nc, ngx);
    gemm2b<<<ngx * 4 * Ed, 512, 131072, stream>>>(hs, w2b, out, n0, nc, ngx);
  }
}

// Round 12
// 323.015 us; speedup vs baseline: 7.7073x; 1.1880x over previous
//
#include <hip/hip_runtime.h>
#include <hip/hip_bf16.h>
#include <stdint.h>

#define Dd 1024
#define Hd 2048
#define Od 1024
#define Ed 8
#define Nd 4096

typedef __bf16 bf16x8 __attribute__((ext_vector_type(8)));
typedef float f32x4 __attribute__((ext_vector_type(4)));
typedef int i32x4 __attribute__((ext_vector_type(4)));

__device__ __forceinline__ void gload16(const void* g, void* l) {
  __builtin_amdgcn_global_load_lds(
      (const __attribute__((address_space(1))) void*)g,
      (__attribute__((address_space(3))) void*)l, 16, 0, 0);
}

__device__ __forceinline__ unsigned short f2bf(float f) {
  __hip_bfloat16 h = __float2bfloat16(f);
  return *reinterpret_cast<unsigned short*>(&h);
}

__device__ __forceinline__ float blockMax256(float v) {
  __shared__ float sm[4];
  #pragma unroll
  for (int o = 32; o > 0; o >>= 1) v = fmaxf(v, __shfl_down(v, o));
  const int lane = threadIdx.x & 63, w = threadIdx.x >> 6;
  if (lane == 0) sm[w] = v;
  __syncthreads();
  return fmaxf(fmaxf(sm[0], sm[1]), fmaxf(sm[2], sm[3]));
}

// ---------- per-row f32 -> i8 quantization (row-max scaling) ----------
template <int K>
__global__ void qrow_kernel(const float* __restrict__ in,
                            signed char* __restrict__ out,
                            float* __restrict__ scale) {
  const int row = blockIdx.x;
  const int t = threadIdx.x;  // 256
  const float* r = in + (size_t)row * K;
  float v[K / 256];
  float m = 0.f;
  #pragma unroll
  for (int i = 0; i < K / 256; ++i) {
    v[i] = r[t + i * 256];
    m = fmaxf(m, fabsf(v[i]));
  }
  const float M = blockMax256(m);
  const float inv = (M > 0.f) ? 127.f / M : 0.f;
  signed char* o = out + (size_t)row * K;
  #pragma unroll
  for (int i = 0; i < K / 256; ++i)
    o[t + i * 256] = (signed char)__float2int_rn(v[i] * inv);
  if (t == 0) scale[row] = M / 127.f;
}

// ---------- f32 -> bf16 conversion, 8 elems / thread ----------
__global__ void cvt_kernel(const float* __restrict__ in,
                           unsigned short* __restrict__ out, int ngroups) {
  int stride = gridDim.x * blockDim.x;
  for (int g = blockIdx.x * blockDim.x + threadIdx.x; g < ngroups; g += stride) {
    const float4* p = (const float4*)(in + (size_t)g * 8);
    float4 a = p[0], b = p[1];
    unsigned short o[8];
    o[0] = f2bf(a.x); o[1] = f2bf(a.y); o[2] = f2bf(a.z); o[3] = f2bf(a.w);
    o[4] = f2bf(b.x); o[5] = f2bf(b.y); o[6] = f2bf(b.z); o[7] = f2bf(b.w);
    *(int4*)(out + (size_t)g * 8) = *(int4*)o;
  }
}

// ---------- router (f32, exact) ----------
__global__ void router_kernel(const float* __restrict__ x, const float* __restrict__ Wr,
                              const float* __restrict__ br, float* __restrict__ route) {
  const int n = blockIdx.x;
  const int t = threadIdx.x;  // 256
  __shared__ float xs[Dd];
  float4 v = *(const float4*)&x[(size_t)n * Dd + t * 4];
  *(float4*)&xs[t * 4] = v;
  __syncthreads();
  float p[Ed];
  #pragma unroll
  for (int e = 0; e < Ed; ++e) p[e] = 0.f;
  for (int d = t; d < Dd; d += 256) {
    float xv = xs[d];
    #pragma unroll
    for (int e = 0; e < Ed; ++e) p[e] += xv * Wr[e * Dd + d];
  }
  __shared__ float red[Ed][4];
  const int lane = t & 63, wid = t >> 6;
  #pragma unroll
  for (int e = 0; e < Ed; ++e) {
    float vv = p[e];
    for (int off = 32; off > 0; off >>= 1) vv += __shfl_down(vv, off);
    if (lane == 0) red[e][wid] = vv;
  }
  __syncthreads();
  if (t == 0) {
    float lg[Ed], mx = -1e30f;
    #pragma unroll
    for (int e = 0; e < Ed; ++e) {
      lg[e] = red[e][0] + red[e][1] + red[e][2] + red[e][3] + br[e];
      mx = fmaxf(mx, lg[e]);
    }
    float s = 0.f;
    #pragma unroll
    for (int e = 0; e < Ed; ++e) { lg[e] = expf(lg[e] - mx); s += lg[e]; }
    float inv = 1.f / s;
    #pragma unroll
    for (int e = 0; e < Ed; ++e) route[(size_t)n * Ed + e] = lg[e] * inv;
  }
}

// ---------- out init: out[n,o] = sum_e route[n,e] * b2[e,o] ----------
__global__ void init_out_kernel(const float* __restrict__ route, const float* __restrict__ b2,
                                float* __restrict__ out) {
  const int idx = blockIdx.x * 256 + threadIdx.x;
  const int n = idx >> 10, o = idx & (Od - 1);
  float s = 0.f;
  #pragma unroll
  for (int e = 0; e < Ed; ++e) s += route[(size_t)n * Ed + e] * b2[e * Od + o];
  out[idx] = s;
}

// ============ GEMM1: i8 256x256, BK=128 B, whole-tile schedule ============
// A=xq[n][D] i8, B=w1q[e][h][D] i8, K=1024, NT=8.
// Epilogue: f = i32*sx[n]*sw1[e,col] + b1 -> relu^2 * route -> hs bf16.
__global__ __launch_bounds__(512, 2) void gemmq1(
    const signed char* __restrict__ Ag,
    const signed char* __restrict__ Bg,
    const float* __restrict__ bias,
    const float* __restrict__ route,
    const float* __restrict__ sA,
    const float* __restrict__ sB,
    unsigned short* __restrict__ hs,
    int n0, int ncRows, int ngx) {
  extern __shared__ char smem[];
  char* As = smem;            // 2 bufs x 32768 B
  char* Bs = smem + 65536;

  const int nwg = gridDim.x;
  const int orig = blockIdx.x;
  const int q8 = nwg >> 3;
  const int wg = (orig & 7) * q8 + (orig >> 3);
  const int bx = wg % ngx;
  const int rem = wg / ngx;
  const int by = rem & 7, ez = rem >> 3;

  const int tid = threadIdx.x;
  const int wid = tid >> 6, lane = tid & 63;
  const int wm = wid >> 2, wn = wid & 3;

  const int KB = Dd;  // bytes/row
  const int NT = KB / 128;

  const signed char* Abase = Ag + (size_t)(n0 + bx * 256) * Dd;
  const signed char* Bbase = Bg + (size_t)ez * Hd * Dd + (size_t)(by * 256) * Dd;

  const int trow = tid >> 3;
  const int tcs = ((tid & 7) ^ (trow & 7)) * 16;

  auto stageA = [&](int buf, int kt, int mh) {
    #pragma unroll
    for (int s = 0; s < 2; ++s) {
      const int pa = mh * 128 + s * 64 + trow;
      const int m = ((pa >> 6) & 1) * 128 + ((pa >> 7) & 1) * 64 + (pa & 63);
      gload16(Abase + (size_t)m * KB + kt * 128 + tcs,
              &As[buf * 32768 + (mh * 128 + s * 64) * 128 + wid * 1024]);
    }
  };
  auto stageB = [&](int buf, int kt, int nh) {
    #pragma unroll
    for (int s = 0; s < 2; ++s) {
      const int pb = nh * 128 + s * 64 + trow;
      const int n = ((pb >> 5) & 3) * 64 + ((pb >> 7) & 1) * 32 + (pb & 31);
      gload16(Bbase + (size_t)n * KB + kt * 128 + tcs,
              &Bs[buf * 32768 + (nh * 128 + s * 64) * 128 + wid * 1024]);
    }
  };

  const int laneRow = lane & 15;
  const int swz[2] = { ((lane >> 4) ^ (lane & 7)) * 16,
                       ((4 + (lane >> 4)) ^ (lane & 7)) * 16 };
  const int aRowB = (wm * 64 + laneRow) * 128;
  const int bRowB = (wn * 32 + laneRow) * 128;

  auto rdA = [&](int buf, int mh, int mi, int kk) -> i32x4 {
    return *(const i32x4*)(As + buf * 32768 + aRowB + (mh * 128 + mi * 16) * 128 + swz[kk]);
  };
  auto rdB = [&](int buf, int nh, int ni, int kk) -> i32x4 {
    return *(const i32x4*)(Bs + buf * 32768 + bRowB + (nh * 128 + ni * 16) * 128 + swz[kk]);
  };

  i32x4 acc[8][4];
  #pragma unroll
  for (int i = 0; i < 8; ++i)
    #pragma unroll
    for (int j = 0; j < 4; ++j) acc[i][j] = (i32x4){0, 0, 0, 0};
  i32x4 a0[4][2], a1[4][2], b0[2][2], b1[2][2];

  stageA(0, 0, 0); stageB(0, 0, 0); stageA(0, 0, 1); stageB(0, 0, 1);
  asm volatile("s_waitcnt vmcnt(0)" ::: "memory");
  __builtin_amdgcn_sched_barrier(0);
  __builtin_amdgcn_s_barrier();

  for (int U = 0; U < NT; ++U) {
    const int buf = U & 1;
    if (U + 1 < NT) {
      stageA(buf ^ 1, U + 1, 0); stageB(buf ^ 1, U + 1, 0);
      stageA(buf ^ 1, U + 1, 1); stageB(buf ^ 1, U + 1, 1);
    }
    #pragma unroll
    for (int mi = 0; mi < 4; ++mi) { a0[mi][0] = rdA(buf, 0, mi, 0); a0[mi][1] = rdA(buf, 0, mi, 1); }
    #pragma unroll
    for (int ni = 0; ni < 2; ++ni) { b0[ni][0] = rdB(buf, 0, ni, 0); b0[ni][1] = rdB(buf, 0, ni, 1); }
    __builtin_amdgcn_s_setprio(1);
    #pragma unroll
    for (int kk = 0; kk < 2; ++kk)
      #pragma unroll
      for (int mi = 0; mi < 4; ++mi)
        #pragma unroll
        for (int ni = 0; ni < 2; ++ni)
          acc[mi][ni] = __builtin_amdgcn_mfma_i32_16x16x64_i8(a0[mi][kk], b0[ni][kk], acc[mi][ni], 0, 0, 0);
    __builtin_amdgcn_s_setprio(0);
    #pragma unroll
    for (int mi = 0; mi < 4; ++mi) { a1[mi][0] = rdA(buf, 1, mi, 0); a1[mi][1] = rdA(buf, 1, mi, 1); }
    __builtin_amdgcn_s_setprio(1);
    #pragma unroll
    for (int kk = 0; kk < 2; ++kk)
      #pragma unroll
      for (int mi = 0; mi < 4; ++mi)
        #pragma unroll
        for (int ni = 0; ni < 2; ++ni)
          acc[4 + mi][ni] = __builtin_amdgcn_mfma_i32_16x16x64_i8(a1[mi][kk], b0[ni][kk], acc[4 + mi][ni], 0, 0, 0);
    __builtin_amdgcn_s_setprio(0);
    #pragma unroll
    for (int ni = 0; ni < 2; ++ni) { b1[ni][0] = rdB(buf, 1, ni, 0); b1[ni][1] = rdB(buf, 1, ni, 1); }
    __builtin_amdgcn_s_setprio(1);
    #pragma unroll
    for (int kk = 0; kk < 2; ++kk)
      #pragma unroll
      for (int mi = 0; mi < 4; ++mi)
        #pragma unroll
        for (int ni = 0; ni < 2; ++ni)
          acc[4 + mi][2 + ni] = __builtin_amdgcn_mfma_i32_16x16x64_i8(a1[mi][kk], b1[ni][kk], acc[4 + mi][2 + ni], 0, 0, 0);
    __builtin_amdgcn_s_setprio(0);
    __builtin_amdgcn_s_setprio(1);
    #pragma unroll
    for (int kk = 0; kk < 2; ++kk)
      #pragma unroll
      for (int mi = 0; mi < 4; ++mi)
        #pragma unroll
        for (int ni = 0; ni < 2; ++ni)
          acc[mi][2 + ni] = __builtin_amdgcn_mfma_i32_16x16x64_i8(a0[mi][kk], b1[ni][kk], acc[mi][2 + ni], 0, 0, 0);
    __builtin_amdgcn_s_setprio(0);
    if (U + 1 < NT) {
      asm volatile("s_waitcnt vmcnt(0)" ::: "memory");
    }
    __builtin_amdgcn_sched_barrier(0);
    __builtin_amdgcn_s_barrier();
  }

  unsigned short* base = hs + (size_t)ez * ((size_t)ncRows * Hd);
  #pragma unroll
  for (int M = 0; M < 8; ++M) {
    const int mh = M >> 2, mi = M & 3;
    const int rowc = bx * 256 + wm * 128 + mh * 64 + mi * 16 + (lane >> 4) * 4;
    float sx4[4], rw[4];
    #pragma unroll
    for (int j = 0; j < 4; ++j) {
      sx4[j] = sA[n0 + rowc + j];
      rw[j] = route[(size_t)(n0 + rowc + j) * Ed + ez];
    }
    #pragma unroll
    for (int N = 0; N < 4; ++N) {
      const int nh = N >> 1, ni = N & 1;
      const int col = by * 256 + wn * 64 + nh * 32 + ni * 16 + (lane & 15);
      const float sw = sB[ez * Hd + col];
      const float bv = bias[ez * Hd + col];
      #pragma unroll
      for (int j = 0; j < 4; ++j) {
        float v = (float)acc[M][N][j] * (sx4[j] * sw) + bv;
        v = fmaxf(v, 0.f);
        v = v * v * rw[j];
        base[(size_t)(rowc + j) * Hd + col] = f2bf(v);
      }
    }
  }
}

// ============ GEMM2: bf16 256x256 z-pair (R6 config), whole-tile schedule ====
// A=hs[e][n][H] bf16, B=w2b[e][o][H] bf16; z-pair: e = 2z + (kt>>5),
// K=2*2048 (NT=64); grid = ngx*4*4 = 256 blocks; atomicAdd -> out.
__global__ __launch_bounds__(512, 2) void gemm2b(
    const unsigned short* __restrict__ Ag,
    const unsigned short* __restrict__ Bg,
    float* __restrict__ out,
    int n0, int ncRows, int ngx) {
  extern __shared__ char smemc[];
  unsigned short* As = (unsigned short*)smemc;          // 2 x 16384 elems
  unsigned short* Bs = (unsigned short*)(smemc + 65536);

  const int nwg = gridDim.x;
  const int orig = blockIdx.x;
  const int q8 = nwg >> 3;
  const int wg = (orig & 7) * q8 + (orig >> 3);
  const int bx = wg % ngx;
  const int rem = wg / ngx;
  const int by = rem & 3, ez = rem >> 2;   // z-pair index in [0,4)

  const int tid = threadIdx.x;
  const int wid = tid >> 6, lane = tid & 63;
  const int wm = wid >> 2, wn = wid & 3;

  const int NT = 2 * Hd / 64;  // 64

  const int trow = tid >> 3;
  const int tcs = ((tid & 7) ^ (trow & 7)) * 8;   // elems

  auto stageA = [&](int buf, int kt, int mh) {
    const int e = ez * 2 + (kt >> 5);
    const size_t Ab = (size_t)e * ncRows * Hd + (size_t)(bx * 256) * Hd;
    const int k0 = (kt & 31) * 64;
    #pragma unroll
    for (int s = 0; s < 2; ++s) {
      const int pa = mh * 128 + s * 64 + trow;
      const int m = ((pa >> 6) & 1) * 128 + ((pa >> 7) & 1) * 64 + (pa & 63);
      gload16(Ag + Ab + (size_t)m * Hd + k0 + tcs,
              &As[(size_t)buf * 16384 + (size_t)(mh * 128 + s * 64) * 64 + wid * 512]);
    }
  };
  auto stageB = [&](int buf, int kt, int nh) {
    const int e = ez * 2 + (kt >> 5);
    const size_t Bb = (size_t)e * Od * Hd + (size_t)(by * 256) * Hd;
    const int k0 = (kt & 31) * 64;
    #pragma unroll
    for (int s = 0; s < 2; ++s) {
      const int pb = nh * 128 + s * 64 + trow;
      const int n = ((pb >> 5) & 3) * 64 + ((pb >> 7) & 1) * 32 + (pb & 31);
      gload16(Bg + Bb + (size_t)n * Hd + k0 + tcs,
              &Bs[(size_t)buf * 16384 + (size_t)(nh * 128 + s * 64) * 64 + wid * 512]);
    }
  };

  const int laneRow = lane & 15;
  const int swzc[2] = { ((lane >> 4) ^ (lane & 7)) << 3,
                        (((lane >> 4) + 4) ^ (lane & 7)) << 3 };
  const int aRowBase = (wm * 64 + laneRow) * 64;
  const int bRowBase = (wn * 32 + laneRow) * 64;

  auto rdA = [&](int buf, int mh, int mi, int kk) -> bf16x8 {
    return *(const bf16x8*)&As[buf * 16384 + aRowBase + (mh * 128 + mi * 16) * 64 + swzc[kk]];
  };
  auto rdB = [&](int buf, int nh, int ni, int kk) -> bf16x8 {
    return *(const bf16x8*)&Bs[buf * 16384 + bRowBase + (nh * 128 + ni * 16) * 64 + swzc[kk]];
  };

  f32x4 acc[8][4];
  #pragma unroll
  for (int i = 0; i < 8; ++i)
    #pragma unroll
    for (int j = 0; j < 4; ++j) acc[i][j] = (f32x4){0.f, 0.f, 0.f, 0.f};
  bf16x8 a0[4][2], a1[4][2], b0[2][2], b1[2][2];

  stageA(0, 0, 0); stageB(0, 0, 0); stageA(0, 0, 1); stageB(0, 0, 1);
  asm volatile("s_waitcnt vmcnt(0)" ::: "memory");
  __builtin_amdgcn_sched_barrier(0);
  __builtin_amdgcn_s_barrier();

  for (int U = 0; U < NT; ++U) {
    const int buf = U & 1;
    if (U + 1 < NT) {
      stageA(buf ^ 1, U + 1, 0); stageB(buf ^ 1, U + 1, 0);
      stageA(buf ^ 1, U + 1, 1); stageB(buf ^ 1, U + 1, 1);
    }
    #pragma unroll
    for (int mi = 0; mi < 4; ++mi) { a0[mi][0] = rdA(buf, 0, mi, 0); a0[mi][1] = rdA(buf, 0, mi, 1); }
    #pragma unroll
    for (int ni = 0; ni < 2; ++ni) { b0[ni][0] = rdB(buf, 0, ni, 0); b0[ni][1] = rdB(buf, 0, ni, 1); }
    __builtin_amdgcn_s_setprio(1);
    #pragma unroll
    for (int kk = 0; kk < 2; ++kk)
      #pragma unroll
      for (int mi = 0; mi < 4; ++mi)
        #pragma unroll
        for (int ni = 0; ni < 2; ++ni)
          acc[mi][ni] = __builtin_amdgcn_mfma_f32_16x16x32_bf16(a0[mi][kk], b0[ni][kk], acc[mi][ni], 0, 0, 0);
    __builtin_amdgcn_s_setprio(0);
    #pragma unroll
    for (int mi = 0; mi < 4; ++mi) { a1[mi][0] = rdA(buf, 1, mi, 0); a1[mi][1] = rdA(buf, 1, mi, 1); }
    __builtin_amdgcn_s_setprio(1);
    #pragma unroll
    for (int kk = 0; kk < 2; ++kk)
      #pragma unroll
      for (int mi = 0; mi < 4; ++mi)
        #pragma unroll
        for (int ni = 0; ni < 2; ++ni)
          acc[4 + mi][ni] = __builtin_amdgcn_mfma_f32_16x16x32_bf16(a1[mi][kk], b0[ni][kk], acc[4 + mi][ni], 0, 0, 0);
    __builtin_amdgcn_s_setprio(0);
    #pragma unroll
    for (int ni = 0; ni < 2; ++ni) { b1[ni][0] = rdB(buf, 1, ni, 0); b1[ni][1] = rdB(buf, 1, ni, 1); }
    __builtin_amdgcn_s_setprio(1);
    #pragma unroll
    for (int kk = 0; kk < 2; ++kk)
      #pragma unroll
      for (int mi = 0; mi < 4; ++mi)
        #pragma unroll
        for (int ni = 0; ni < 2; ++ni)
          acc[4 + mi][2 + ni] = __builtin_amdgcn_mfma_f32_16x16x32_bf16(a1[mi][kk], b1[ni][kk], acc[4 + mi][2 + ni], 0, 0, 0);
    __builtin_amdgcn_s_setprio(0);
    __builtin_amdgcn_s_setprio(1);
    #pragma unroll
    for (int kk = 0; kk < 2; ++kk)
      #pragma unroll
      for (int mi = 0; mi < 4; ++mi)
        #pragma unroll
        for (int ni = 0; ni < 2; ++ni)
          acc[mi][2 + ni] = __builtin_amdgcn_mfma_f32_16x16x32_bf16(a0[mi][kk], b1[ni][kk], acc[mi][2 + ni], 0, 0, 0);
    __builtin_amdgcn_s_setprio(0);
    if (U + 1 < NT) {
      asm volatile("s_waitcnt vmcnt(0)" ::: "memory");
    }
    __builtin_amdgcn_sched_barrier(0);
    __builtin_amdgcn_s_barrier();
  }

  #pragma unroll
  for (int M = 0; M < 8; ++M) {
    const int mh = M >> 2, mi = M & 3;
    const int row = n0 + bx * 256 + wm * 128 + mh * 64 + mi * 16 + (lane >> 4) * 4;
    #pragma unroll
    for (int N = 0; N < 4; ++N) {
      const int nh = N >> 1, ni = N & 1;
      const int col = by * 256 + wn * 64 + nh * 32 + ni * 16 + (lane & 15);
      #pragma unroll
      for (int j = 0; j < 4; ++j)
        atomicAdd(out + (size_t)(row + j) * Od + col, acc[M][N][j]);
    }
  }
}

extern "C" void kernel_launch(void* const* d_in, const int* in_sizes, int n_in,
                              void* d_out, int out_size, void* d_ws, size_t ws_size,
                              hipStream_t stream) {
  const float* x  = (const float*)d_in[0];
  const float* Wr = (const float*)d_in[1];
  const float* br = (const float*)d_in[2];
  const float* W1 = (const float*)d_in[3];
  const float* b1 = (const float*)d_in[4];
  const float* W2 = (const float*)d_in[5];
  const float* b2 = (const float*)d_in[6];
  float* out = (float*)d_out;

  char* ws = (char*)d_ws;
  size_t off = 0;
  auto alloc = [&](size_t bytes) { char* p = ws + off; off += (bytes + 255) & ~255ULL; return p; };
  float* route = (float*)alloc((size_t)Nd * Ed * 4);
  float* sx    = (float*)alloc((size_t)Nd * 4);
  float* sw1   = (float*)alloc((size_t)Ed * Hd * 4);
  signed char* xq  = (signed char*)alloc((size_t)Nd * Dd);
  signed char* w1q = (signed char*)alloc((size_t)Ed * Hd * Dd);
  unsigned short* w2b = (unsigned short*)alloc((size_t)Ed * Od * Hd * 2);
  unsigned short* hs = (unsigned short*)(ws + off);

  size_t remain = (ws_size > off) ? (ws_size - off) : 0;
  const size_t perRow = (size_t)Ed * Hd * 2;  // bytes of hs per token row
  long long ncMax = (long long)(remain / perRow);
  int NC = (int)(ncMax & ~255LL);
  if (NC > Nd) NC = Nd;
  if (NC < 256) NC = 256;

  hipFuncSetAttribute(reinterpret_cast<const void*>(&gemmq1),
                      hipFuncAttributeMaxDynamicSharedMemorySize, 131072);
  hipFuncSetAttribute(reinterpret_cast<const void*>(&gemm2b),
                      hipFuncAttributeMaxDynamicSharedMemorySize, 131072);

  qrow_kernel<Dd><<<Nd, 256, 0, stream>>>(x, xq, sx);
  qrow_kernel<Dd><<<Ed * Hd, 256, 0, stream>>>(W1, w1q, sw1);
  cvt_kernel<<<2048, 256, 0, stream>>>(W2, w2b, Ed * Od * Hd / 8);
  router_kernel<<<Nd, 256, 0, stream>>>(x, Wr, br, route);
  init_out_kernel<<<Nd * Od / 256, 256, 0, stream>>>(route, b2, out);

  for (int n0 = 0; n0 < Nd; n0 += NC) {
    int nc = (NC < (Nd - n0)) ? NC : (Nd - n0);
    int ngx = nc / 256;
    gemmq1<<<ngx * 8 * Ed, 512, 131072, stream>>>(
        xq, w1q, b1, route, sx, sw1, hs, n0, nc, ngx);
    gemm2b<<<ngx * 4 * 4, 512, 131072, stream>>>(hs, w2b, out, n0, nc, ngx);
  }
}

// Round 13
// 297.751 us; speedup vs baseline: 8.3613x; 1.0849x over previous
//
#include <hip/hip_runtime.h>
#include <hip/hip_bf16.h>
#include <stdint.h>

#define Dd 1024
#define Hd 2048
#define Od 1024
#define Ed 8
#define Nd 4096

typedef __bf16 bf16x8 __attribute__((ext_vector_type(8)));
typedef float f32x4 __attribute__((ext_vector_type(4)));
typedef int i32x4 __attribute__((ext_vector_type(4)));

__device__ __forceinline__ void gload16(const void* g, void* l) {
  __builtin_amdgcn_global_load_lds(
      (const __attribute__((address_space(1))) void*)g,
      (__attribute__((address_space(3))) void*)l, 16, 0, 0);
}

__device__ __forceinline__ unsigned short f2bf(float f) {
  __hip_bfloat16 h = __float2bfloat16(f);
  return *reinterpret_cast<unsigned short*>(&h);
}

__device__ __forceinline__ float blockMax256(float v) {
  __shared__ float sm[4];
  #pragma unroll
  for (int o = 32; o > 0; o >>= 1) v = fmaxf(v, __shfl_down(v, o));
  const int lane = threadIdx.x & 63, w = threadIdx.x >> 6;
  if (lane == 0) sm[w] = v;
  __syncthreads();
  return fmaxf(fmaxf(sm[0], sm[1]), fmaxf(sm[2], sm[3]));
}

// ---------- per-row f32 -> i8 quantization (row-max scaling) ----------
template <int K>
__global__ void qrow_kernel(const float* __restrict__ in,
                            signed char* __restrict__ out,
                            float* __restrict__ scale) {
  const int row = blockIdx.x;
  const int t = threadIdx.x;  // 256
  const float* r = in + (size_t)row * K;
  float v[K / 256];
  float m = 0.f;
  #pragma unroll
  for (int i = 0; i < K / 256; ++i) {
    v[i] = r[t + i * 256];
    m = fmaxf(m, fabsf(v[i]));
  }
  const float M = blockMax256(m);
  const float inv = (M > 0.f) ? 127.f / M : 0.f;
  signed char* o = out + (size_t)row * K;
  #pragma unroll
  for (int i = 0; i < K / 256; ++i)
    o[t + i * 256] = (signed char)__float2int_rn(v[i] * inv);
  if (t == 0) scale[row] = M / 127.f;
}

// ---------- fused router: route softmax + x i8-quant + out init ----------
__global__ void router_kernel(const float* __restrict__ x, const float* __restrict__ Wr,
                              const float* __restrict__ br, const float* __restrict__ b2,
                              float* __restrict__ route,
                              signed char* __restrict__ xq, float* __restrict__ sx,
                              float* __restrict__ out) {
  const int n = blockIdx.x;
  const int t = threadIdx.x;  // 256
  __shared__ float xs[Dd];
  float4 v = *(const float4*)&x[(size_t)n * Dd + t * 4];
  *(float4*)&xs[t * 4] = v;
  // x row-max quant (blockMax256 has the syncthreads that also publishes xs)
  float m = fmaxf(fmaxf(fabsf(v.x), fabsf(v.y)), fmaxf(fabsf(v.z), fabsf(v.w)));
  const float M = blockMax256(m);
  const float inv = (M > 0.f) ? 127.f / M : 0.f;
  int q0 = __float2int_rn(v.x * inv) & 255, q1 = __float2int_rn(v.y * inv) & 255;
  int q2 = __float2int_rn(v.z * inv) & 255, q3 = __float2int_rn(v.w * inv) & 255;
  *(int*)(xq + (size_t)n * Dd + t * 4) = q0 | (q1 << 8) | (q2 << 16) | (q3 << 24);
  if (t == 0) sx[n] = M / 127.f;

  float p[Ed];
  #pragma unroll
  for (int e = 0; e < Ed; ++e) p[e] = 0.f;
  for (int d = t; d < Dd; d += 256) {
    float xv = xs[d];
    #pragma unroll
    for (int e = 0; e < Ed; ++e) p[e] += xv * Wr[e * Dd + d];
  }
  __shared__ float red[Ed][4];
  const int lane = t & 63, wid = t >> 6;
  #pragma unroll
  for (int e = 0; e < Ed; ++e) {
    float vv = p[e];
    for (int off = 32; off > 0; off >>= 1) vv += __shfl_down(vv, off);
    if (lane == 0) red[e][wid] = vv;
  }
  __syncthreads();
  __shared__ float rsm[Ed];
  if (t == 0) {
    float lg[Ed], mx = -1e30f;
    #pragma unroll
    for (int e = 0; e < Ed; ++e) {
      lg[e] = red[e][0] + red[e][1] + red[e][2] + red[e][3] + br[e];
      mx = fmaxf(mx, lg[e]);
    }
    float s = 0.f;
    #pragma unroll
    for (int e = 0; e < Ed; ++e) { lg[e] = expf(lg[e] - mx); s += lg[e]; }
    float is = 1.f / s;
    #pragma unroll
    for (int e = 0; e < Ed; ++e) {
      float rv = lg[e] * is;
      route[(size_t)n * Ed + e] = rv;
      rsm[e] = rv;
    }
  }
  __syncthreads();
  // out init: out[n,o] = sum_e route[n,e]*b2[e,o], 4 cols/thread
  float4 acc = {0.f, 0.f, 0.f, 0.f};
  #pragma unroll
  for (int e = 0; e < Ed; ++e) {
    float4 bv = *(const float4*)&b2[e * Od + t * 4];
    float rv = rsm[e];
    acc.x += rv * bv.x; acc.y += rv * bv.y; acc.z += rv * bv.z; acc.w += rv * bv.w;
  }
  *(float4*)&out[(size_t)n * Od + t * 4] = acc;
}

// ============ GEMM1: i8 256x256, BK=128 B, whole-tile schedule ============
// A=xq[n][D] i8, B=w1q[e][h][D] i8, K=1024, NT=8.
// Epilogue: f = i32*sx[n]*sw1[e,col] + b1 -> relu^2 * route -> hs bf16.
// Side job: W2 f32->bf16 cvt interleaved into the K-loop stall slots
// (256 groups of 8 elems per iteration; independent traffic, drained by the
// existing boundary vmcnt(0); w2b complete before gemm2b launches, stream order).
__global__ __launch_bounds__(512, 2) void gemmq1(
    const signed char* __restrict__ Ag,
    const signed char* __restrict__ Bg,
    const float* __restrict__ bias,
    const float* __restrict__ route,
    const float* __restrict__ sA,
    const float* __restrict__ sB,
    unsigned short* __restrict__ hs,
    const float* __restrict__ W2f,
    unsigned short* __restrict__ w2cv,
    int cvtGroups,
    int n0, int ncRows, int ngx) {
  extern __shared__ char smem[];
  char* As = smem;            // 2 bufs x 32768 B
  char* Bs = smem + 65536;

  const int nwg = gridDim.x;
  const int orig = blockIdx.x;
  const int q8 = nwg >> 3;
  const int wg = (orig & 7) * q8 + (orig >> 3);
  const int bx = wg % ngx;
  const int rem = wg / ngx;
  const int by = rem & 7, ez = rem >> 3;

  const int tid = threadIdx.x;
  const int wid = tid >> 6, lane = tid & 63;
  const int wm = wid >> 2, wn = wid & 3;

  const int KB = Dd;  // bytes/row
  const int NT = KB / 128;

  // W2-cvt quota for this block
  const int cvtPerBlk = (cvtGroups + nwg - 1) / nwg;
  const int cvtBase = orig * cvtPerBlk;
  const int cvtEnd = (cvtBase + cvtPerBlk < cvtGroups) ? cvtBase + cvtPerBlk : cvtGroups;
  const int perIter = (cvtPerBlk + NT - 1) / NT;

  const signed char* Abase = Ag + (size_t)(n0 + bx * 256) * Dd;
  const signed char* Bbase = Bg + (size_t)ez * Hd * Dd + (size_t)(by * 256) * Dd;

  const int trow = tid >> 3;
  const int tcs = ((tid & 7) ^ (trow & 7)) * 16;

  auto stageA = [&](int buf, int kt, int mh) {
    #pragma unroll
    for (int s = 0; s < 2; ++s) {
      const int pa = mh * 128 + s * 64 + trow;
      const int m = ((pa >> 6) & 1) * 128 + ((pa >> 7) & 1) * 64 + (pa & 63);
      gload16(Abase + (size_t)m * KB + kt * 128 + tcs,
              &As[buf * 32768 + (mh * 128 + s * 64) * 128 + wid * 1024]);
    }
  };
  auto stageB = [&](int buf, int kt, int nh) {
    #pragma unroll
    for (int s = 0; s < 2; ++s) {
      const int pb = nh * 128 + s * 64 + trow;
      const int n = ((pb >> 5) & 3) * 64 + ((pb >> 7) & 1) * 32 + (pb & 31);
      gload16(Bbase + (size_t)n * KB + kt * 128 + tcs,
              &Bs[buf * 32768 + (nh * 128 + s * 64) * 128 + wid * 1024]);
    }
  };

  const int laneRow = lane & 15;
  const int swz[2] = { ((lane >> 4) ^ (lane & 7)) * 16,
                       ((4 + (lane >> 4)) ^ (lane & 7)) * 16 };
  const int aRowB = (wm * 64 + laneRow) * 128;
  const int bRowB = (wn * 32 + laneRow) * 128;

  auto rdA = [&](int buf, int mh, int mi, int kk) -> i32x4 {
    return *(const i32x4*)(As + buf * 32768 + aRowB + (mh * 128 + mi * 16) * 128 + swz[kk]);
  };
  auto rdB = [&](int buf, int nh, int ni, int kk) -> i32x4 {
    return *(const i32x4*)(Bs + buf * 32768 + bRowB + (nh * 128 + ni * 16) * 128 + swz[kk]);
  };

  i32x4 acc[8][4];
  #pragma unroll
  for (int i = 0; i < 8; ++i)
    #pragma unroll
    for (int j = 0; j < 4; ++j) acc[i][j] = (i32x4){0, 0, 0, 0};
  i32x4 a0[4][2], a1[4][2], b0[2][2], b1[2][2];

  stageA(0, 0, 0); stageB(0, 0, 0); stageA(0, 0, 1); stageB(0, 0, 1);
  asm volatile("s_waitcnt vmcnt(0)" ::: "memory");
  __builtin_amdgcn_sched_barrier(0);
  __builtin_amdgcn_s_barrier();

  for (int U = 0; U < NT; ++U) {
    const int buf = U & 1;
    if (U + 1 < NT) {
      stageA(buf ^ 1, U + 1, 0); stageB(buf ^ 1, U + 1, 0);
      stageA(buf ^ 1, U + 1, 1); stageB(buf ^ 1, U + 1, 1);
    }
    // interleaved W2 cvt slice (rides the stall slots)
    for (int r = 0; r < perIter; r += 512) {
      const int idx = r + tid;
      const int g = cvtBase + U * perIter + idx;
      if (idx < perIter && g < cvtEnd) {
        const float4* p = (const float4*)(W2f + (size_t)g * 8);
        float4 a = p[0], b = p[1];
        unsigned short o[8];
        o[0] = f2bf(a.x); o[1] = f2bf(a.y); o[2] = f2bf(a.z); o[3] = f2bf(a.w);
        o[4] = f2bf(b.x); o[5] = f2bf(b.y); o[6] = f2bf(b.z); o[7] = f2bf(b.w);
        *(int4*)(w2cv + (size_t)g * 8) = *(int4*)o;
      }
    }
    #pragma unroll
    for (int mi = 0; mi < 4; ++mi) { a0[mi][0] = rdA(buf, 0, mi, 0); a0[mi][1] = rdA(buf, 0, mi, 1); }
    #pragma unroll
    for (int ni = 0; ni < 2; ++ni) { b0[ni][0] = rdB(buf, 0, ni, 0); b0[ni][1] = rdB(buf, 0, ni, 1); }
    __builtin_amdgcn_s_setprio(1);
    #pragma unroll
    for (int kk = 0; kk < 2; ++kk)
      #pragma unroll
      for (int mi = 0; mi < 4; ++mi)
        #pragma unroll
        for (int ni = 0; ni < 2; ++ni)
          acc[mi][ni] = __builtin_amdgcn_mfma_i32_16x16x64_i8(a0[mi][kk], b0[ni][kk], acc[mi][ni], 0, 0, 0);
    __builtin_amdgcn_s_setprio(0);
    #pragma unroll
    for (int mi = 0; mi < 4; ++mi) { a1[mi][0] = rdA(buf, 1, mi, 0); a1[mi][1] = rdA(buf, 1, mi, 1); }
    __builtin_amdgcn_s_setprio(1);
    #pragma unroll
    for (int kk = 0; kk < 2; ++kk)
      #pragma unroll
      for (int mi = 0; mi < 4; ++mi)
        #pragma unroll
        for (int ni = 0; ni < 2; ++ni)
          acc[4 + mi][ni] = __builtin_amdgcn_mfma_i32_16x16x64_i8(a1[mi][kk], b0[ni][kk], acc[4 + mi][ni], 0, 0, 0);
    __builtin_amdgcn_s_setprio(0);
    #pragma unroll
    for (int ni = 0; ni < 2; ++ni) { b1[ni][0] = rdB(buf, 1, ni, 0); b1[ni][1] = rdB(buf, 1, ni, 1); }
    __builtin_amdgcn_s_setprio(1);
    #pragma unroll
    for (int kk = 0; kk < 2; ++kk)
      #pragma unroll
      for (int mi = 0; mi < 4; ++mi)
        #pragma unroll
        for (int ni = 0; ni < 2; ++ni)
          acc[4 + mi][2 + ni] = __builtin_amdgcn_mfma_i32_16x16x64_i8(a1[mi][kk], b1[ni][kk], acc[4 + mi][2 + ni], 0, 0, 0);
    __builtin_amdgcn_s_setprio(0);
    __builtin_amdgcn_s_setprio(1);
    #pragma unroll
    for (int kk = 0; kk < 2; ++kk)
      #pragma unroll
      for (int mi = 0; mi < 4; ++mi)
        #pragma unroll
        for (int ni = 0; ni < 2; ++ni)
          acc[mi][2 + ni] = __builtin_amdgcn_mfma_i32_16x16x64_i8(a0[mi][kk], b1[ni][kk], acc[mi][2 + ni], 0, 0, 0);
    __builtin_amdgcn_s_setprio(0);
    if (U + 1 < NT) {
      asm volatile("s_waitcnt vmcnt(0)" ::: "memory");
    }
    __builtin_amdgcn_sched_barrier(0);
    __builtin_amdgcn_s_barrier();
  }

  unsigned short* base = hs + (size_t)ez * ((size_t)ncRows * Hd);
  #pragma unroll
  for (int M = 0; M < 8; ++M) {
    const int mh = M >> 2, mi = M & 3;
    const int rowc = bx * 256 + wm * 128 + mh * 64 + mi * 16 + (lane >> 4) * 4;
    float sx4[4], rw[4];
    #pragma unroll
    for (int j = 0; j < 4; ++j) {
      sx4[j] = sA[n0 + rowc + j];
      rw[j] = route[(size_t)(n0 + rowc + j) * Ed + ez];
    }
    #pragma unroll
    for (int N = 0; N < 4; ++N) {
      const int nh = N >> 1, ni = N & 1;
      const int col = by * 256 + wn * 64 + nh * 32 + ni * 16 + (lane & 15);
      const float sw = sB[ez * Hd + col];
      const float bv = bias[ez * Hd + col];
      #pragma unroll
      for (int j = 0; j < 4; ++j) {
        float v = (float)acc[M][N][j] * (sx4[j] * sw) + bv;
        v = fmaxf(v, 0.f);
        v = v * v * rw[j];
        base[(size_t)(rowc + j) * Hd + col] = f2bf(v);
      }
    }
  }
}

// ============ GEMM2: bf16 256x256 z-pair, whole-tile schedule ====
// A=hs[e][n][H] bf16, B=w2b[e][o][H] bf16; z-pair: e = 2z + (kt>>5),
// K=2*2048 (NT=64); grid = ngx*4*4; atomicAdd -> out.
__global__ __launch_bounds__(512, 2) void gemm2b(
    const unsigned short* __restrict__ Ag,
    const unsigned short* __restrict__ Bg,
    float* __restrict__ out,
    int n0, int ncRows, int ngx) {
  extern __shared__ char smemc[];
  unsigned short* As = (unsigned short*)smemc;          // 2 x 16384 elems
  unsigned short* Bs = (unsigned short*)(smemc + 65536);

  const int nwg = gridDim.x;
  const int orig = blockIdx.x;
  const int q8 = nwg >> 3;
  const int wg = (orig & 7) * q8 + (orig >> 3);
  const int bx = wg % ngx;
  const int rem = wg / ngx;
  const int by = rem & 3, ez = rem >> 2;   // z-pair index in [0,4)

  const int tid = threadIdx.x;
  const int wid = tid >> 6, lane = tid & 63;
  const int wm = wid >> 2, wn = wid & 3;

  const int NT = 2 * Hd / 64;  // 64

  const int trow = tid >> 3;
  const int tcs = ((tid & 7) ^ (trow & 7)) * 8;   // elems

  auto stageA = [&](int buf, int kt, int mh) {
    const int e = ez * 2 + (kt >> 5);
    const size_t Ab = (size_t)e * ncRows * Hd + (size_t)(bx * 256) * Hd;
    const int k0 = (kt & 31) * 64;
    #pragma unroll
    for (int s = 0; s < 2; ++s) {
      const int pa = mh * 128 + s * 64 + trow;
      const int m = ((pa >> 6) & 1) * 128 + ((pa >> 7) & 1) * 64 + (pa & 63);
      gload16(Ag + Ab + (size_t)m * Hd + k0 + tcs,
              &As[(size_t)buf * 16384 + (size_t)(mh * 128 + s * 64) * 64 + wid * 512]);
    }
  };
  auto stageB = [&](int buf, int kt, int nh) {
    const int e = ez * 2 + (kt >> 5);
    const size_t Bb = (size_t)e * Od * Hd + (size_t)(by * 256) * Hd;
    const int k0 = (kt & 31) * 64;
    #pragma unroll
    for (int s = 0; s < 2; ++s) {
      const int pb = nh * 128 + s * 64 + trow;
      const int n = ((pb >> 5) & 3) * 64 + ((pb >> 7) & 1) * 32 + (pb & 31);
      gload16(Bg + Bb + (size_t)n * Hd + k0 + tcs,
              &Bs[(size_t)buf * 16384 + (size_t)(nh * 128 + s * 64) * 64 + wid * 512]);
    }
  };

  const int laneRow = lane & 15;
  const int swzc[2] = { ((lane >> 4) ^ (lane & 7)) << 3,
                        (((lane >> 4) + 4) ^ (lane & 7)) << 3 };
  const int aRowBase = (wm * 64 + laneRow) * 64;
  const int bRowBase = (wn * 32 + laneRow) * 64;

  auto rdA = [&](int buf, int mh, int mi, int kk) -> bf16x8 {
    return *(const bf16x8*)&As[buf * 16384 + aRowBase + (mh * 128 + mi * 16) * 64 + swzc[kk]];
  };
  auto rdB = [&](int buf, int nh, int ni, int kk) -> bf16x8 {
    return *(const bf16x8*)&Bs[buf * 16384 + bRowBase + (nh * 128 + ni * 16) * 64 + swzc[kk]];
  };

  f32x4 acc[8][4];
  #pragma unroll
  for (int i = 0; i < 8; ++i)
    #pragma unroll
    for (int j = 0; j < 4; ++j) acc[i][j] = (f32x4){0.f, 0.f, 0.f, 0.f};
  bf16x8 a0[4][2], a1[4][2], b0[2][2], b1[2][2];

  stageA(0, 0, 0); stageB(0, 0, 0); stageA(0, 0, 1); stageB(0, 0, 1);
  asm volatile("s_waitcnt vmcnt(0)" ::: "memory");
  __builtin_amdgcn_sched_barrier(0);
  __builtin_amdgcn_s_barrier();

  for (int U = 0; U < NT; ++U) {
    const int buf = U & 1;
    if (U + 1 < NT) {
      stageA(buf ^ 1, U + 1, 0); stageB(buf ^ 1, U + 1, 0);
      stageA(buf ^ 1, U + 1, 1); stageB(buf ^ 1, U + 1, 1);
    }
    #pragma unroll
    for (int mi = 0; mi < 4; ++mi) { a0[mi][0] = rdA(buf, 0, mi, 0); a0[mi][1] = rdA(buf, 0, mi, 1); }
    #pragma unroll
    for (int ni = 0; ni < 2; ++ni) { b0[ni][0] = rdB(buf, 0, ni, 0); b0[ni][1] = rdB(buf, 0, ni, 1); }
    __builtin_amdgcn_s_setprio(1);
    #pragma unroll
    for (int kk = 0; kk < 2; ++kk)
      #pragma unroll
      for (int mi = 0; mi < 4; ++mi)
        #pragma unroll
        for (int ni = 0; ni < 2; ++ni)
          acc[mi][ni] = __builtin_amdgcn_mfma_f32_16x16x32_bf16(a0[mi][kk], b0[ni][kk], acc[mi][ni], 0, 0, 0);
    __builtin_amdgcn_s_setprio(0);
    #pragma unroll
    for (int mi = 0; mi < 4; ++mi) { a1[mi][0] = rdA(buf, 1, mi, 0); a1[mi][1] = rdA(buf, 1, mi, 1); }
    __builtin_amdgcn_s_setprio(1);
    #pragma unroll
    for (int kk = 0; kk < 2; ++kk)
      #pragma unroll
      for (int mi = 0; mi < 4; ++mi)
        #pragma unroll
        for (int ni = 0; ni < 2; ++ni)
          acc[4 + mi][ni] = __builtin_amdgcn_mfma_f32_16x16x32_bf16(a1[mi][kk], b0[ni][kk], acc[4 + mi][ni], 0, 0, 0);
    __builtin_amdgcn_s_setprio(0);
    #pragma unroll
    for (int ni = 0; ni < 2; ++ni) { b1[ni][0] = rdB(buf, 1, ni, 0); b1[ni][1] = rdB(buf, 1, ni, 1); }
    __builtin_amdgcn_s_setprio(1);
    #pragma unroll
    for (int kk = 0; kk < 2; ++kk)
      #pragma unroll
      for (int mi = 0; mi < 4; ++mi)
        #pragma unroll
        for (int ni = 0; ni < 2; ++ni)
          acc[4 + mi][2 + ni] = __builtin_amdgcn_mfma_f32_16x16x32_bf16(a1[mi][kk], b1[ni][kk], acc[4 + mi][2 + ni], 0, 0, 0);
    __builtin_amdgcn_s_setprio(0);
    __builtin_amdgcn_s_setprio(1);
    #pragma unroll
    for (int kk = 0; kk < 2; ++kk)
      #pragma unroll
      for (int mi = 0; mi < 4; ++mi)
        #pragma unroll
        for (int ni = 0; ni < 2; ++ni)
          acc[mi][2 + ni] = __builtin_amdgcn_mfma_f32_16x16x32_bf16(a0[mi][kk], b1[ni][kk], acc[mi][2 + ni], 0, 0, 0);
    __builtin_amdgcn_s_setprio(0);
    if (U + 1 < NT) {
      asm volatile("s_waitcnt vmcnt(0)" ::: "memory");
    }
    __builtin_amdgcn_sched_barrier(0);
    __builtin_amdgcn_s_barrier();
  }

  #pragma unroll
  for (int M = 0; M < 8; ++M) {
    const int mh = M >> 2, mi = M & 3;
    const int row = n0 + bx * 256 + wm * 128 + mh * 64 + mi * 16 + (lane >> 4) * 4;
    #pragma unroll
    for (int N = 0; N < 4; ++N) {
      const int nh = N >> 1, ni = N & 1;
      const int col = by * 256 + wn * 64 + nh * 32 + ni * 16 + (lane & 15);
      #pragma unroll
      for (int j = 0; j < 4; ++j)
        atomicAdd(out + (size_t)(row + j) * Od + col, acc[M][N][j]);
    }
  }
}

extern "C" void kernel_launch(void* const* d_in, const int* in_sizes, int n_in,
                              void* d_out, int out_size, void* d_ws, size_t ws_size,
                              hipStream_t stream) {
  const float* x  = (const float*)d_in[0];
  const float* Wr = (const float*)d_in[1];
  const float* br = (const float*)d_in[2];
  const float* W1 = (const float*)d_in[3];
  const float* b1 = (const float*)d_in[4];
  const float* W2 = (const float*)d_in[5];
  const float* b2 = (const float*)d_in[6];
  float* out = (float*)d_out;

  char* ws = (char*)d_ws;
  size_t off = 0;
  auto alloc = [&](size_t bytes) { char* p = ws + off; off += (bytes + 255) & ~255ULL; return p; };
  float* route = (float*)alloc((size_t)Nd * Ed * 4);
  float* sx    = (float*)alloc((size_t)Nd * 4);
  float* sw1   = (float*)alloc((size_t)Ed * Hd * 4);
  signed char* xq  = (signed char*)alloc((size_t)Nd * Dd);
  signed char* w1q = (signed char*)alloc((size_t)Ed * Hd * Dd);
  unsigned short* w2b = (unsigned short*)alloc((size_t)Ed * Od * Hd * 2);
  unsigned short* hs = (unsigned short*)(ws + off);

  size_t remain = (ws_size > off) ? (ws_size - off) : 0;
  const size_t perRow = (size_t)Ed * Hd * 2;  // bytes of hs per token row
  long long ncMax = (long long)(remain / perRow);
  int NC = (int)(ncMax & ~255LL);
  if (NC > Nd) NC = Nd;
  if (NC < 256) NC = 256;

  hipFuncSetAttribute(reinterpret_cast<const void*>(&gemmq1),
                      hipFuncAttributeMaxDynamicSharedMemorySize, 131072);
  hipFuncSetAttribute(reinterpret_cast<const void*>(&gemm2b),
                      hipFuncAttributeMaxDynamicSharedMemorySize, 131072);

  qrow_kernel<Dd><<<Ed * Hd, 256, 0, stream>>>(W1, w1q, sw1);
  router_kernel<<<Nd, 256, 0, stream>>>(x, Wr, br, b2, route, xq, sx, out);

  const int cvtGroups = Ed * Od * Hd / 8;  // W2 bf16-cvt groups (8 f32 each)
  bool first = true;
  for (int n0 = 0; n0 < Nd; n0 += NC) {
    int nc = (NC < (Nd - n0)) ? NC : (Nd - n0);
    int ngx = nc / 256;
    gemmq1<<<ngx * 8 * Ed, 512, 131072, stream>>>(
        xq, w1q, b1, route, sx, sw1, hs, W2, w2b,
        first ? cvtGroups : 0, n0, nc, ngx);
    first = false;
    gemm2b<<<ngx * 4 * 4, 512, 131072, stream>>>(hs, w2b, out, n0, nc, ngx);
  }
}